// Round 11
// baseline (1693.550 us; speedup 1.0000x reference)
//
#include <hip/hip_runtime.h>
#include <hip/hip_fp16.h>

// TFNN: 3-layer TransformerConv GNN.
// Round 11: round-10 + (1) degree-bucketed node permutation (equal trip counts
// per wave), (2) q/k/v interleaved per node, (3) conflict-free we_s layout.

#define D 128

typedef _Float16 half8 __attribute__((ext_vector_type(8)));
typedef float f32x4 __attribute__((ext_vector_type(4)));

// ---------------- CSR build ----------------
__global__ __launch_bounds__(256) void hist_kernel(const int* __restrict__ dst,
                                                   int* __restrict__ counts, int e) {
  int i = blockIdx.x * 256 + threadIdx.x;
  if (i < e) atomicAdd(&counts[dst[i]], 1);
}

__global__ __launch_bounds__(256) void scan_a_kernel(const int* __restrict__ counts,
                                                     int* __restrict__ incl,
                                                     int* __restrict__ bsum) {
  int gid = blockIdx.x * 256 + threadIdx.x;
  int lane = threadIdx.x & 63, wid = threadIdx.x >> 6;
  int v = counts[gid];
  int s = v;
  #pragma unroll
  for (int off = 1; off < 64; off <<= 1) {
    int t = __shfl_up(s, off, 64);
    if (lane >= off) s += t;
  }
  __shared__ int wsum[4];
  if (lane == 63) wsum[wid] = s;
  __syncthreads();
  #pragma unroll
  for (int w = 0; w < 3; ++w)
    if (wid > w) s += wsum[w];
  incl[gid] = s;
  if (threadIdx.x == 255) bsum[blockIdx.x] = s;
}

__global__ __launch_bounds__(512) void scan_b_kernel(int* __restrict__ bs) {
  int tid = threadIdx.x;
  int lane = tid & 63, wid = tid >> 6;
  int v = bs[tid];
  int s = v;
  #pragma unroll
  for (int off = 1; off < 64; off <<= 1) {
    int t = __shfl_up(s, off, 64);
    if (lane >= off) s += t;
  }
  __shared__ int wsum[8];
  if (lane == 63) wsum[wid] = s;
  __syncthreads();
  #pragma unroll
  for (int w = 0; w < 7; ++w)
    if (wid > w) s += wsum[w];
  bs[tid] = s - v;  // exclusive block prefix
}

__global__ __launch_bounds__(256) void scan_c_kernel(const int* __restrict__ incl,
                                                     const int* __restrict__ counts,
                                                     const int* __restrict__ bsum,
                                                     int* __restrict__ offs, int n, int e) {
  int gid = blockIdx.x * 256 + threadIdx.x;
  if (gid < n) offs[gid] = incl[gid] - counts[gid] + bsum[blockIdx.x];
  if (gid == 0) offs[n] = e;
}

__global__ __launch_bounds__(256) void scatter_kernel(const int* __restrict__ srcs,
                                                      const int* __restrict__ dsts,
                                                      const int* __restrict__ offs,
                                                      int* __restrict__ cursor,
                                                      int* __restrict__ csr_src,
                                                      int* __restrict__ csr_eid, int e) {
  int i = blockIdx.x * 256 + threadIdx.x;
  if (i >= e) return;
  int d = dsts[i];
  int slot = atomicAdd(&cursor[d], 1);
  int p = offs[d] + slot;
  csr_src[p] = srcs[i];
  csr_eid[p] = i;
}

// deterministic order: sort each node's incoming edge list by edge id
__global__ __launch_bounds__(256) void sort_kernel(const int* __restrict__ offs,
                                                   int* __restrict__ eid,
                                                   int* __restrict__ srcs, int n) {
  int i = blockIdx.x * 256 + threadIdx.x;
  if (i >= n) return;
  int b = offs[i], e = offs[i + 1];
  for (int p = b + 1; p < e; ++p) {
    int ke = eid[p], ks = srcs[p];
    int q = p - 1;
    while (q >= b && eid[q] > ke) {
      eid[q + 1] = eid[q]; srcs[q + 1] = srcs[q]; --q;
    }
    eid[q + 1] = ke; srcs[q + 1] = ks;
  }
}

// ---------------- degree-bucketed node permutation ----------------
__global__ __launch_bounds__(256) void hist_deg_kernel(const int* __restrict__ counts,
                                                       int* __restrict__ hist32, int n) {
  int i = blockIdx.x * 256 + threadIdx.x;
  if (i < n) atomicAdd(&hist32[min(counts[i], 31)], 1);
}

__global__ __launch_bounds__(64) void scan32_kernel(int* __restrict__ h) {
  int lane = threadIdx.x;
  int v = (lane < 32) ? h[lane] : 0;
  int s = v;
  #pragma unroll
  for (int off = 1; off < 32; off <<= 1) {
    int t = __shfl_up(s, off, 64);
    if (lane >= off) s += t;
  }
  if (lane < 32) h[lane] = s - v;  // exclusive base
}

__global__ __launch_bounds__(256) void scatter_deg_kernel(const int* __restrict__ counts,
                                                          const int* __restrict__ hist32,
                                                          int* __restrict__ hcur32,
                                                          int* __restrict__ perm, int n) {
  int i = blockIdx.x * 256 + threadIdx.x;
  if (i >= n) return;
  int b = min(counts[i], 31);
  int pos = hist32[b] + atomicAdd(&hcur32[b], 1);
  perm[pos] = i;
}

// ---------------- weight transpose + fp16 convert: out[n][kk] = W[kk][n] ----------------
__global__ __launch_bounds__(256) void convw_kernel(const float* __restrict__ W,
                                                    __half* __restrict__ out,
                                                    int ncols, int K) {
  int idx = blockIdx.x * 256 + threadIdx.x;
  if (idx >= ncols * K) return;
  int n = idx / K, kk = idx - n * K;
  out[idx] = __float2half(W[(size_t)kk * ncols + n]);
}

// Wqe[f][kk] = sum_d we[f,d]*Wq[kk,d] -> fp16; bqe[f] = sum_d we[f,d]*bq[d]
__global__ __launch_bounds__(256) void convwe_kernel(const float* __restrict__ we,
                                                     const float* __restrict__ Wq,
                                                     const float* __restrict__ bq,
                                                     __half* __restrict__ outW,
                                                     float* __restrict__ outB) {
  int idx = blockIdx.x * 256 + threadIdx.x;
  if (idx < 2048) {
    int f = idx >> 7, kk = idx & 127;
    float s = 0.f;
    for (int d = 0; d < 128; ++d) s += we[f * 128 + d] * Wq[kk * 128 + d];
    outW[f * 128 + kk] = __float2half(s);
  } else if (idx < 2064) {
    int f = idx - 2048;
    float s = 0.f;
    for (int d = 0; d < 128; ++d) s += we[f * 128 + d] * bq[d];
    outB[f] = s;
  }
}

// bias concat: out[0:512] = bq|bk|bv|bs
__global__ __launch_bounds__(256) void bcat_kernel(const float* __restrict__ bq,
                                                   const float* __restrict__ bk,
                                                   const float* __restrict__ bv,
                                                   const float* __restrict__ bs,
                                                   float* __restrict__ out) {
  int j = blockIdx.x * 256 + threadIdx.x;
  if (j >= 512) return;
  const float* src = (j < 128) ? bq : (j < 256) ? bk : (j < 384) ? bv : bs;
  out[j] = src[j & 127];
}

// ---------------- typed stores / loads ----------------
__device__ inline void store4h(__half* p, float4 v) {
  __half2 h01 = __floats2half2_rn(v.x, v.y);
  __half2 h23 = __floats2half2_rn(v.z, v.w);
  uint2 u;
  u.x = *(unsigned int*)&h01;
  u.y = *(unsigned int*)&h23;
  *(uint2*)p = u;
}

__device__ inline void load8h(const __half* p, float4& lo, float4& hi) {
  uint4 u = *(const uint4*)p;
  float2 a = __half22float2(*(__half2*)&u.x);
  float2 b = __half22float2(*(__half2*)&u.y);
  float2 c = __half22float2(*(__half2*)&u.z);
  float2 d = __half22float2(*(__half2*)&u.w);
  lo = make_float4(a.x, a.y, b.x, b.y);
  hi = make_float4(c.x, c.y, d.x, d.y);
}

// ---------------- MFMA GEMM (LDS-staged W chunks + optional 16-col t-tile) ----------------
// in [Nrows][K] fp32; Wt [(NCT*16 + (QKVS?16:0))][K] fp16; bias matching fp32.
// QKVS: cols 0-127 -> qkv[row][0:128] (q), 128-255 -> qkv[row][128:256] (k),
// 256-383 -> qkv[row][256:384] (v) (fp16, row stride 384), 384-511 -> os (fp32,
// may alias `in`: each lane fully reads its own row before any store),
// cols 512-527 -> qt fp32 [Nrows][16] (t = we@q per node).
template <int K, int NCT, bool QKVS>
__global__ __launch_bounds__(256) void mfma_gemm_kernel(
    const float* in, const __half* __restrict__ Wt, const float* __restrict__ bias,
    __half* __restrict__ qkv, float* os, float* __restrict__ qt) {
  constexpr int WST = K + 8;  // Wc row stride in halfs; (K+8)*2 bytes % 16 == 0
  __shared__ alignas(16) __half Wc[128 * WST];  // current 128-col W chunk
  const int tid = threadIdx.x;
  const int w = tid >> 6, l = tid & 63;
  const int lo = l & 15, hi = l >> 4;
  const size_t row = (size_t)blockIdx.x * 64 + w * 16 + lo;

  // A-side (h) fragments: 8 consecutive fp32 of own row per k-step, cvt fp16
  half8 af[K / 32];
  #pragma unroll
  for (int s = 0; s < K / 32; ++s) {
    const float* sp = in + row * K + s * 32 + hi * 8;
    float4 f0 = *(const float4*)sp;
    float4 f1 = *(const float4*)(sp + 4);
    half8 a;
    a[0] = (_Float16)f0.x; a[1] = (_Float16)f0.y; a[2] = (_Float16)f0.z; a[3] = (_Float16)f0.w;
    a[4] = (_Float16)f1.x; a[5] = (_Float16)f1.y; a[6] = (_Float16)f1.z; a[7] = (_Float16)f1.w;
    af[s] = a;
  }

  // chunk loop: 128 output cols per chunk, W chunk staged in LDS
  #pragma unroll 1
  for (int ch = 0; ch < NCT / 8; ++ch) {
    __syncthreads();  // protect Wc reuse across chunks
    #pragma unroll
    for (int i = 0; i < 128 * K / 8 / 256; ++i) {
      int idx = i * 256 + tid;
      int col = idx / (K / 8), kk = (idx % (K / 8)) * 8;
      *(uint4*)&Wc[col * WST + kk] =
          *(const uint4*)(Wt + (size_t)(ch * 128 + col) * K + kk);
    }
    __syncthreads();

    #pragma unroll
    for (int t = 0; t < 8; ++t) {
      f32x4 c = {0.f, 0.f, 0.f, 0.f};
      #pragma unroll
      for (int s = 0; s < K / 32; ++s) {
        half8 bf = *(const half8*)&Wc[(t * 16 + lo) * WST + s * 32 + hi * 8];
        c = __builtin_amdgcn_mfma_f32_16x16x32_f16(bf, af[s], c, 0, 0, 0);
      }
      const int col0 = ch * 128 + t * 16 + hi * 4;
      float4 b4 = *(const float4*)(bias + col0);
      float4 o;
      o.x = c[0] + b4.x; o.y = c[1] + b4.y; o.z = c[2] + b4.z; o.w = c[3] + b4.w;
      if (QKVS) {
        const int mid = col0 >> 7, cc = col0 & 127;
        if (mid < 3) store4h(qkv + row * 384 + mid * 128 + cc, o);
        else         *(float4*)(os + row * 128 + cc) = o;
      } else {
        *(float4*)(os + row * 128 + col0) = o;
      }
    }
  }

  // t-tile: 16 extra cols (Wqe rows 512..527) -> qt[row][0..15]
  if constexpr (QKVS) {
    __syncthreads();  // last chunk's MFMAs done reading Wc
    {
      int col = tid >> 4;          // K/8 == 16 -> exactly 256 vec4 copies
      int kk = (tid & 15) * 8;
      *(uint4*)&Wc[col * WST + kk] =
          *(const uint4*)(Wt + (size_t)(512 + col) * K + kk);
    }
    __syncthreads();
    f32x4 c = {0.f, 0.f, 0.f, 0.f};
    #pragma unroll
    for (int s = 0; s < K / 32; ++s) {
      half8 bf = *(const half8*)&Wc[lo * WST + s * 32 + hi * 8];
      c = __builtin_amdgcn_mfma_f32_16x16x32_f16(bf, af[s], c, 0, 0, 0);
    }
    float4 b4 = *(const float4*)(bias + 512 + hi * 4);
    float4 o;
    o.x = c[0] + b4.x; o.y = c[1] + b4.y; o.z = c[2] + b4.z; o.w = c[3] + b4.w;
    *(float4*)(qt + row * 16 + hi * 4) = o;
  }
}

// ---------------- node-centric transformer conv: 4 nodes per wave ----------------
// 16-lane group per node (nodes taken from degree-sorted perm), 8 dims/lane.
// h holds s on entry; writes relu(s + (accV + accE@we)/den).
__global__ __launch_bounds__(256) void node_kernel(
    const __half* __restrict__ qkv, float* __restrict__ h,
    const float* __restrict__ edge_attr,
    const float* __restrict__ we, const float* __restrict__ tq,
    const int* __restrict__ offs, const int* __restrict__ csr_src,
    const int* __restrict__ csr_eid, const int* __restrict__ perm) {
  // we_s: stride-10 layout (feature f, lane-chunk sub, elem j) -> f*160+sub*10+j
  __shared__ float we_s[16 * 160];  // 10 KB, conflict-free reads
  for (int i = threadIdx.x; i < 2048; i += 256) {
    int f = i >> 7, d = i & 127;
    we_s[f * 160 + (d >> 3) * 10 + (d & 7)] = we[i];
  }
  __syncthreads();

  const int lane = threadIdx.x & 63;
  const int wid = threadIdx.x >> 6;
  const int g = lane >> 4, sub = lane & 15;
  const int nid = perm[blockIdx.x * 16 + wid * 4 + g];
  const int d0 = sub * 8;
  const float inv_sqrt_d = 0.08838834764831845f;  // 1/sqrt(128)

  float4 qlo, qhi;
  load8h(qkv + (size_t)nid * 384 + d0, qlo, qhi);
  float4 slo = *(const float4*)(h + (size_t)nid * D + d0);
  float4 shi = *(const float4*)(h + (size_t)nid * D + d0 + 4);
  const float tf = tq[(size_t)nid * 16 + sub];

  const int eb = offs[nid], ee = offs[nid + 1];
  float m = -3.0e38f, den = 0.f, accE = 0.f;
  float4 alo = {0.f, 0.f, 0.f, 0.f}, ahi = {0.f, 0.f, 0.f, 0.f};

  // 2-deep pipeline over this group's edges
  float4 klon = {0,0,0,0}, khin = {0,0,0,0}, vlon = {0,0,0,0}, vhin = {0,0,0,0};
  float eafn = 0.f;
  int p = eb;
  if (p < ee) {
    int src = csr_src[p];
    int eid = csr_eid[p];
    load8h(qkv + (size_t)src * 384 + 128 + d0, klon, khin);
    load8h(qkv + (size_t)src * 384 + 256 + d0, vlon, vhin);
    eafn = edge_attr[(size_t)eid * 16 + sub];
  }
  while (p < ee) {
    float4 klo = klon, khi = khin, vlo = vlon, vhi = vhin;
    float eaf = eafn;
    ++p;
    if (p < ee) {
      int src = csr_src[p];
      int eid = csr_eid[p];
      load8h(qkv + (size_t)src * 384 + 128 + d0, klon, khin);
      load8h(qkv + (size_t)src * 384 + 256 + d0, vlon, vhin);
      eafn = edge_attr[(size_t)eid * 16 + sub];
    }
    float pa = qlo.x * klo.x + qlo.y * klo.y + qlo.z * klo.z + qlo.w * klo.w +
               qhi.x * khi.x + qhi.y * khi.y + qhi.z * khi.z + qhi.w * khi.w +
               eaf * tf;
    #pragma unroll
    for (int off = 8; off > 0; off >>= 1) pa += __shfl_xor(pa, off, 64);
    pa *= inv_sqrt_d;
    float mn = fmaxf(m, pa);
    float esc = __expf(m - mn);
    float ew = __expf(pa - mn);
    den = den * esc + ew;
    alo.x = alo.x * esc + ew * vlo.x;
    alo.y = alo.y * esc + ew * vlo.y;
    alo.z = alo.z * esc + ew * vlo.z;
    alo.w = alo.w * esc + ew * vlo.w;
    ahi.x = ahi.x * esc + ew * vhi.x;
    ahi.y = ahi.y * esc + ew * vhi.y;
    ahi.z = ahi.z * esc + ew * vhi.z;
    ahi.w = ahi.w * esc + ew * vhi.w;
    accE = accE * esc + ew * eaf;
    m = mn;
  }

  if (den > 0.f) {
    float inv = 1.0f / den;
    float4 elo = {0.f, 0.f, 0.f, 0.f}, ehi = {0.f, 0.f, 0.f, 0.f};
    const int gbase = lane & 48;
    const int wb = sub * 10;
    #pragma unroll
    for (int f = 0; f < 16; ++f) {
      float aE = __shfl(accE, gbase + f, 64);
      const float* wr = &we_s[f * 160 + wb];
      float2 w01 = *(const float2*)(wr + 0);
      float2 w23 = *(const float2*)(wr + 2);
      float2 w45 = *(const float2*)(wr + 4);
      float2 w67 = *(const float2*)(wr + 6);
      elo.x += aE * w01.x; elo.y += aE * w01.y; elo.z += aE * w23.x; elo.w += aE * w23.y;
      ehi.x += aE * w45.x; ehi.y += aE * w45.y; ehi.z += aE * w67.x; ehi.w += aE * w67.y;
    }
    slo.x += (alo.x + elo.x) * inv;
    slo.y += (alo.y + elo.y) * inv;
    slo.z += (alo.z + elo.z) * inv;
    slo.w += (alo.w + elo.w) * inv;
    shi.x += (ahi.x + ehi.x) * inv;
    shi.y += (ahi.y + ehi.y) * inv;
    shi.z += (ahi.z + ehi.z) * inv;
    shi.w += (ahi.w + ehi.w) * inv;
  }
  slo.x = fmaxf(slo.x, 0.f); slo.y = fmaxf(slo.y, 0.f);
  slo.z = fmaxf(slo.z, 0.f); slo.w = fmaxf(slo.w, 0.f);
  shi.x = fmaxf(shi.x, 0.f); shi.y = fmaxf(shi.y, 0.f);
  shi.z = fmaxf(shi.z, 0.f); shi.w = fmaxf(shi.w, 0.f);
  *(float4*)(h + (size_t)nid * D + d0) = slo;
  *(float4*)(h + (size_t)nid * D + d0 + 4) = shi;
}

// ---------------- segmented mean-pool (batch sorted) ----------------
__global__ __launch_bounds__(64) void pool_kernel(const float* __restrict__ h,
                                                  const int* __restrict__ batch,
                                                  float* __restrict__ hg,
                                                  float* __restrict__ cnt, int n) {
  int base = blockIdx.x * 128;
  int lane = threadIdx.x;
  float2 acc = {0.f, 0.f};
  float run = 0.f;
  int cur = batch[base];
  for (int i = 0; i < 128; ++i) {
    int node = base + i;
    int g = batch[node];
    if (g != cur) {
      atomicAdd(&hg[(size_t)cur * D + 2 * lane], acc.x);
      atomicAdd(&hg[(size_t)cur * D + 2 * lane + 1], acc.y);
      if (lane == 0) atomicAdd(&cnt[cur], run);
      acc.x = acc.y = 0.f; run = 0.f; cur = g;
    }
    float2 hv = *(const float2*)(h + (size_t)node * D + 2 * lane);
    acc.x += hv.x; acc.y += hv.y; run += 1.f;
  }
  atomicAdd(&hg[(size_t)cur * D + 2 * lane], acc.x);
  atomicAdd(&hg[(size_t)cur * D + 2 * lane + 1], acc.y);
  if (lane == 0) atomicAdd(&cnt[cur], run);
}

// ---------------- head: mean, fc2+relu, fc3 (one wave per graph) ----------------
__global__ __launch_bounds__(256) void head_kernel(const float* __restrict__ hg,
                                                   const float* __restrict__ cnt,
                                                   const float* __restrict__ w2,
                                                   const float* __restrict__ b2,
                                                   const float* __restrict__ w3,
                                                   const float* __restrict__ b3,
                                                   float* __restrict__ out) {
  __shared__ float w2s[128 * 16];
  __shared__ float rowb[4][128];
  for (int i = threadIdx.x; i < (128 * 16) / 4; i += 256)
    ((float4*)w2s)[i] = ((const float4*)w2)[i];
  int wid = threadIdx.x >> 6, lane = threadIdx.x & 63;
  int g = blockIdx.x * 4 + wid;
  float inv = 1.0f / fmaxf(cnt[g], 1.0f);
  rowb[wid][lane] = hg[(size_t)g * D + lane] * inv;
  rowb[wid][lane + 64] = hg[(size_t)g * D + 64 + lane] * inv;
  __syncthreads();
  float t = 0.f;
  if (lane < 16) {
    float a = b2[lane];
    for (int d = 0; d < 128; ++d) a += rowb[wid][d] * w2s[d * 16 + lane];
    t = fmaxf(a, 0.f) * w3[lane];
  }
  #pragma unroll
  for (int off = 8; off > 0; off >>= 1) t += __shfl_xor(t, off, 64);
  if (lane == 0) out[g] = t + b3[0];
}

// ---------------- launch ----------------
extern "C" void kernel_launch(void* const* d_in, const int* in_sizes, int n_in,
                              void* d_out, int out_size, void* d_ws, size_t ws_size,
                              hipStream_t stream) {
  const float* x = (const float*)d_in[0];
  const int* eidx = (const int*)d_in[1];
  const float* eattr = (const float*)d_in[2];
  const int* batch = (const int*)d_in[3];
  const float* fc1_w = (const float*)d_in[4];
  const float* fc1_b = (const float*)d_in[5];
  const float* WQ[3] = {(const float*)d_in[6], (const float*)d_in[15], (const float*)d_in[24]};
  const float* BQ[3] = {(const float*)d_in[7], (const float*)d_in[16], (const float*)d_in[25]};
  const float* WK[3] = {(const float*)d_in[8], (const float*)d_in[17], (const float*)d_in[26]};
  const float* BK[3] = {(const float*)d_in[9], (const float*)d_in[18], (const float*)d_in[27]};
  const float* WV[3] = {(const float*)d_in[10], (const float*)d_in[19], (const float*)d_in[28]};
  const float* BV[3] = {(const float*)d_in[11], (const float*)d_in[20], (const float*)d_in[29]};
  const float* WE[3] = {(const float*)d_in[12], (const float*)d_in[21], (const float*)d_in[30]};
  const float* WS[3] = {(const float*)d_in[13], (const float*)d_in[22], (const float*)d_in[31]};
  const float* BS[3] = {(const float*)d_in[14], (const float*)d_in[23], (const float*)d_in[32]};
  const float* fc2_w = (const float*)d_in[33];
  const float* fc2_b = (const float*)d_in[34];
  const float* fc3_w = (const float*)d_in[35];
  const float* fc3_b = (const float*)d_in[36];

  const int N = in_sizes[0] / 64;
  const int E = in_sizes[1] / 2;
  const int G = out_size;  // DIM_OUT = 1
  const int* srcs = eidx;
  const int* dsts = eidx + E;
  const size_t ND = (size_t)N * D;

  char* base = (char*)d_ws;
  size_t off = 0;
  auto alloc = [&](size_t bytes) {
    void* p = base + off;
    off = (off + bytes + 255) & ~(size_t)255;
    return p;
  };
  // zeroed region first: hg, cnt, counts, cursor, hist32, hcur32
  float* hg = (float*)alloc((size_t)G * D * 4);
  float* cntf = (float*)alloc((size_t)G * 4);
  int* counts = (int*)alloc((size_t)N * 4);
  int* cursor = (int*)alloc((size_t)N * 4);
  int* hist32 = (int*)alloc(32 * 4);
  int* hcur32 = (int*)alloc(32 * 4);
  size_t zero_bytes = off;
  int* incl = (int*)alloc((size_t)N * 4);
  int* offs = (int*)alloc((size_t)(N + 4) * 4);
  int* bsum = (int*)alloc(512 * 4);
  int* csr_src = (int*)alloc((size_t)E * 4);
  int* csr_eid = (int*)alloc((size_t)E * 4);
  int* perm = (int*)alloc((size_t)N * 4);
  float* h = (float*)alloc(ND * 4);
  __half* qkv = (__half*)alloc((size_t)N * 384 * 2);
  float* qt = (float*)alloc((size_t)N * 16 * 4);
  __half* Wt[3];
  float* bc[3];
  for (int l = 0; l < 3; ++l) {
    Wt[l] = (__half*)alloc(528 * 128 * 2);  // q|k|v|s (512) + Wqe (16)
    bc[l] = (float*)alloc(544 * 4);         // 512 biases + 16 bqe
  }
  __half* fc1t = (__half*)alloc(128 * 64 * 2);
  if (off > ws_size) return;  // ws too small (diagnostic: stub-identical absmax)

  hipMemsetAsync(hg, 0, zero_bytes, stream);

  // weight prep: transpose+fp16 (q|k|v|s per layer), Wqe/bqe, bias concat, fc1
  for (int l = 0; l < 3; ++l) {
    convw_kernel<<<64, 256, 0, stream>>>(WQ[l], Wt[l] + 0 * 16384, 128, 128);
    convw_kernel<<<64, 256, 0, stream>>>(WK[l], Wt[l] + 1 * 16384, 128, 128);
    convw_kernel<<<64, 256, 0, stream>>>(WV[l], Wt[l] + 2 * 16384, 128, 128);
    convw_kernel<<<64, 256, 0, stream>>>(WS[l], Wt[l] + 3 * 16384, 128, 128);
    convwe_kernel<<<9, 256, 0, stream>>>(WE[l], WQ[l], BQ[l],
                                         Wt[l] + 4 * 16384, bc[l] + 512);
    bcat_kernel<<<2, 256, 0, stream>>>(BQ[l], BK[l], BV[l], BS[l], bc[l]);
  }
  convw_kernel<<<32, 256, 0, stream>>>(fc1_w, fc1t, 128, 64);

  // CSR build (deterministic after sort) + degree-bucketed node permutation
  hist_kernel<<<E / 256, 256, 0, stream>>>(dsts, counts, E);
  hist_deg_kernel<<<N / 256, 256, 0, stream>>>(counts, hist32, N);
  scan32_kernel<<<1, 64, 0, stream>>>(hist32);
  scatter_deg_kernel<<<N / 256, 256, 0, stream>>>(counts, hist32, hcur32, perm, N);
  scan_a_kernel<<<N / 256, 256, 0, stream>>>(counts, incl, bsum);
  scan_b_kernel<<<1, 512, 0, stream>>>(bsum);
  scan_c_kernel<<<N / 256, 256, 0, stream>>>(incl, counts, bsum, offs, N, E);
  scatter_kernel<<<E / 256, 256, 0, stream>>>(srcs, dsts, offs, cursor, csr_src, csr_eid, E);
  sort_kernel<<<N / 256, 256, 0, stream>>>(offs, csr_eid, csr_src, N);

  // fc1: h = x @ fc1_w + fc1_b  (MFMA, K=64, 128 cols)
  mfma_gemm_kernel<64, 8, false><<<N / 64, 256, 0, stream>>>(
      x, fc1t, fc1_b, nullptr, h, nullptr);

  // 3 transformer-conv layers
  for (int l = 0; l < 3; ++l) {
    mfma_gemm_kernel<128, 32, true><<<N / 64, 256, 0, stream>>>(
        h, Wt[l], bc[l], qkv, h, qt);
    node_kernel<<<N / 16, 256, 0, stream>>>(qkv, h, eattr, WE[l], qt,
                                            offs, csr_src, csr_eid, perm);
  }

  // mean pool + head
  pool_kernel<<<N / 128, 64, 0, stream>>>(h, batch, hg, cntf, N);
  head_kernel<<<G / 4, 256, 0, stream>>>(hg, cntf, fc2_w, fc2_b, fc3_w, fc3_b, (float*)d_out);
}

// Round 12
// 632.332 us; speedup vs baseline: 2.6783x; 2.6783x over previous
//
#include <hip/hip_runtime.h>
#include <hip/hip_fp16.h>

// TFNN: 3-layer TransformerConv GNN.
// Round 12: round-10 base (sequential node order — locality matters) +
// qkv interleaved per node + conflict-free we_s layout. Perm machinery
// deleted (atomic-return contention cost 530us; balance gain was nil).

#define D 128

typedef _Float16 half8 __attribute__((ext_vector_type(8)));
typedef float f32x4 __attribute__((ext_vector_type(4)));

// ---------------- CSR build ----------------
__global__ __launch_bounds__(256) void hist_kernel(const int* __restrict__ dst,
                                                   int* __restrict__ counts, int e) {
  int i = blockIdx.x * 256 + threadIdx.x;
  if (i < e) atomicAdd(&counts[dst[i]], 1);
}

__global__ __launch_bounds__(256) void scan_a_kernel(const int* __restrict__ counts,
                                                     int* __restrict__ incl,
                                                     int* __restrict__ bsum) {
  int gid = blockIdx.x * 256 + threadIdx.x;
  int lane = threadIdx.x & 63, wid = threadIdx.x >> 6;
  int v = counts[gid];
  int s = v;
  #pragma unroll
  for (int off = 1; off < 64; off <<= 1) {
    int t = __shfl_up(s, off, 64);
    if (lane >= off) s += t;
  }
  __shared__ int wsum[4];
  if (lane == 63) wsum[wid] = s;
  __syncthreads();
  #pragma unroll
  for (int w = 0; w < 3; ++w)
    if (wid > w) s += wsum[w];
  incl[gid] = s;
  if (threadIdx.x == 255) bsum[blockIdx.x] = s;
}

__global__ __launch_bounds__(512) void scan_b_kernel(int* __restrict__ bs) {
  int tid = threadIdx.x;
  int lane = tid & 63, wid = tid >> 6;
  int v = bs[tid];
  int s = v;
  #pragma unroll
  for (int off = 1; off < 64; off <<= 1) {
    int t = __shfl_up(s, off, 64);
    if (lane >= off) s += t;
  }
  __shared__ int wsum[8];
  if (lane == 63) wsum[wid] = s;
  __syncthreads();
  #pragma unroll
  for (int w = 0; w < 7; ++w)
    if (wid > w) s += wsum[w];
  bs[tid] = s - v;  // exclusive block prefix
}

__global__ __launch_bounds__(256) void scan_c_kernel(const int* __restrict__ incl,
                                                     const int* __restrict__ counts,
                                                     const int* __restrict__ bsum,
                                                     int* __restrict__ offs, int n, int e) {
  int gid = blockIdx.x * 256 + threadIdx.x;
  if (gid < n) offs[gid] = incl[gid] - counts[gid] + bsum[blockIdx.x];
  if (gid == 0) offs[n] = e;
}

__global__ __launch_bounds__(256) void scatter_kernel(const int* __restrict__ srcs,
                                                      const int* __restrict__ dsts,
                                                      const int* __restrict__ offs,
                                                      int* __restrict__ cursor,
                                                      int* __restrict__ csr_src,
                                                      int* __restrict__ csr_eid, int e) {
  int i = blockIdx.x * 256 + threadIdx.x;
  if (i >= e) return;
  int d = dsts[i];
  int slot = atomicAdd(&cursor[d], 1);
  int p = offs[d] + slot;
  csr_src[p] = srcs[i];
  csr_eid[p] = i;
}

// deterministic order: sort each node's incoming edge list by edge id
__global__ __launch_bounds__(256) void sort_kernel(const int* __restrict__ offs,
                                                   int* __restrict__ eid,
                                                   int* __restrict__ srcs, int n) {
  int i = blockIdx.x * 256 + threadIdx.x;
  if (i >= n) return;
  int b = offs[i], e = offs[i + 1];
  for (int p = b + 1; p < e; ++p) {
    int ke = eid[p], ks = srcs[p];
    int q = p - 1;
    while (q >= b && eid[q] > ke) {
      eid[q + 1] = eid[q]; srcs[q + 1] = srcs[q]; --q;
    }
    eid[q + 1] = ke; srcs[q + 1] = ks;
  }
}

// ---------------- weight transpose + fp16 convert: out[n][kk] = W[kk][n] ----------------
__global__ __launch_bounds__(256) void convw_kernel(const float* __restrict__ W,
                                                    __half* __restrict__ out,
                                                    int ncols, int K) {
  int idx = blockIdx.x * 256 + threadIdx.x;
  if (idx >= ncols * K) return;
  int n = idx / K, kk = idx - n * K;
  out[idx] = __float2half(W[(size_t)kk * ncols + n]);
}

// Wqe[f][kk] = sum_d we[f,d]*Wq[kk,d] -> fp16; bqe[f] = sum_d we[f,d]*bq[d]
__global__ __launch_bounds__(256) void convwe_kernel(const float* __restrict__ we,
                                                     const float* __restrict__ Wq,
                                                     const float* __restrict__ bq,
                                                     __half* __restrict__ outW,
                                                     float* __restrict__ outB) {
  int idx = blockIdx.x * 256 + threadIdx.x;
  if (idx < 2048) {
    int f = idx >> 7, kk = idx & 127;
    float s = 0.f;
    for (int d = 0; d < 128; ++d) s += we[f * 128 + d] * Wq[kk * 128 + d];
    outW[f * 128 + kk] = __float2half(s);
  } else if (idx < 2064) {
    int f = idx - 2048;
    float s = 0.f;
    for (int d = 0; d < 128; ++d) s += we[f * 128 + d] * bq[d];
    outB[f] = s;
  }
}

// bias concat: out[0:512] = bq|bk|bv|bs
__global__ __launch_bounds__(256) void bcat_kernel(const float* __restrict__ bq,
                                                   const float* __restrict__ bk,
                                                   const float* __restrict__ bv,
                                                   const float* __restrict__ bs,
                                                   float* __restrict__ out) {
  int j = blockIdx.x * 256 + threadIdx.x;
  if (j >= 512) return;
  const float* src = (j < 128) ? bq : (j < 256) ? bk : (j < 384) ? bv : bs;
  out[j] = src[j & 127];
}

// ---------------- typed stores / loads ----------------
__device__ inline void store4h(__half* p, float4 v) {
  __half2 h01 = __floats2half2_rn(v.x, v.y);
  __half2 h23 = __floats2half2_rn(v.z, v.w);
  uint2 u;
  u.x = *(unsigned int*)&h01;
  u.y = *(unsigned int*)&h23;
  *(uint2*)p = u;
}

__device__ inline void load8h(const __half* p, float4& lo, float4& hi) {
  uint4 u = *(const uint4*)p;
  float2 a = __half22float2(*(__half2*)&u.x);
  float2 b = __half22float2(*(__half2*)&u.y);
  float2 c = __half22float2(*(__half2*)&u.z);
  float2 d = __half22float2(*(__half2*)&u.w);
  lo = make_float4(a.x, a.y, b.x, b.y);
  hi = make_float4(c.x, c.y, d.x, d.y);
}

// ---------------- MFMA GEMM (LDS-staged W chunks + optional 16-col t-tile) ----------------
// in [Nrows][K] fp32; Wt [(NCT*16 + (QKVS?16:0))][K] fp16; bias matching fp32.
// QKVS: cols 0-127 -> qkv[row][0:128] (q), 128-255 -> qkv[row][128:256] (k),
// 256-383 -> qkv[row][256:384] (v) (fp16, row stride 384), 384-511 -> os (fp32,
// may alias `in`: each lane fully reads its own row before any store),
// cols 512-527 -> qt fp32 [Nrows][16] (t = we@q per node).
template <int K, int NCT, bool QKVS>
__global__ __launch_bounds__(256) void mfma_gemm_kernel(
    const float* in, const __half* __restrict__ Wt, const float* __restrict__ bias,
    __half* __restrict__ qkv, float* os, float* __restrict__ qt) {
  constexpr int WST = K + 8;  // Wc row stride in halfs; (K+8)*2 bytes % 16 == 0
  __shared__ alignas(16) __half Wc[128 * WST];  // current 128-col W chunk
  const int tid = threadIdx.x;
  const int w = tid >> 6, l = tid & 63;
  const int lo = l & 15, hi = l >> 4;
  const size_t row = (size_t)blockIdx.x * 64 + w * 16 + lo;

  // A-side (h) fragments: 8 consecutive fp32 of own row per k-step, cvt fp16
  half8 af[K / 32];
  #pragma unroll
  for (int s = 0; s < K / 32; ++s) {
    const float* sp = in + row * K + s * 32 + hi * 8;
    float4 f0 = *(const float4*)sp;
    float4 f1 = *(const float4*)(sp + 4);
    half8 a;
    a[0] = (_Float16)f0.x; a[1] = (_Float16)f0.y; a[2] = (_Float16)f0.z; a[3] = (_Float16)f0.w;
    a[4] = (_Float16)f1.x; a[5] = (_Float16)f1.y; a[6] = (_Float16)f1.z; a[7] = (_Float16)f1.w;
    af[s] = a;
  }

  // chunk loop: 128 output cols per chunk, W chunk staged in LDS
  #pragma unroll 1
  for (int ch = 0; ch < NCT / 8; ++ch) {
    __syncthreads();  // protect Wc reuse across chunks
    #pragma unroll
    for (int i = 0; i < 128 * K / 8 / 256; ++i) {
      int idx = i * 256 + tid;
      int col = idx / (K / 8), kk = (idx % (K / 8)) * 8;
      *(uint4*)&Wc[col * WST + kk] =
          *(const uint4*)(Wt + (size_t)(ch * 128 + col) * K + kk);
    }
    __syncthreads();

    #pragma unroll
    for (int t = 0; t < 8; ++t) {
      f32x4 c = {0.f, 0.f, 0.f, 0.f};
      #pragma unroll
      for (int s = 0; s < K / 32; ++s) {
        half8 bf = *(const half8*)&Wc[(t * 16 + lo) * WST + s * 32 + hi * 8];
        c = __builtin_amdgcn_mfma_f32_16x16x32_f16(bf, af[s], c, 0, 0, 0);
      }
      const int col0 = ch * 128 + t * 16 + hi * 4;
      float4 b4 = *(const float4*)(bias + col0);
      float4 o;
      o.x = c[0] + b4.x; o.y = c[1] + b4.y; o.z = c[2] + b4.z; o.w = c[3] + b4.w;
      if (QKVS) {
        const int mid = col0 >> 7, cc = col0 & 127;
        if (mid < 3) store4h(qkv + row * 384 + mid * 128 + cc, o);
        else         *(float4*)(os + row * 128 + cc) = o;
      } else {
        *(float4*)(os + row * 128 + col0) = o;
      }
    }
  }

  // t-tile: 16 extra cols (Wqe rows 512..527) -> qt[row][0..15]
  if constexpr (QKVS) {
    __syncthreads();  // last chunk's MFMAs done reading Wc
    {
      int col = tid >> 4;          // K/8 == 16 -> exactly 256 vec4 copies
      int kk = (tid & 15) * 8;
      *(uint4*)&Wc[col * WST + kk] =
          *(const uint4*)(Wt + (size_t)(512 + col) * K + kk);
    }
    __syncthreads();
    f32x4 c = {0.f, 0.f, 0.f, 0.f};
    #pragma unroll
    for (int s = 0; s < K / 32; ++s) {
      half8 bf = *(const half8*)&Wc[lo * WST + s * 32 + hi * 8];
      c = __builtin_amdgcn_mfma_f32_16x16x32_f16(bf, af[s], c, 0, 0, 0);
    }
    float4 b4 = *(const float4*)(bias + 512 + hi * 4);
    float4 o;
    o.x = c[0] + b4.x; o.y = c[1] + b4.y; o.z = c[2] + b4.z; o.w = c[3] + b4.w;
    *(float4*)(qt + row * 16 + hi * 4) = o;
  }
}

// ---------------- node-centric transformer conv: 4 nodes per wave ----------------
// 16-lane group per node (sequential node ids -> wave reads 4 consecutive
// rows), 8 dims/lane. h holds s on entry; writes relu(s + (accV+accE@we)/den).
__global__ __launch_bounds__(256) void node_kernel(
    const __half* __restrict__ qkv, float* __restrict__ h,
    const float* __restrict__ edge_attr,
    const float* __restrict__ we, const float* __restrict__ tq,
    const int* __restrict__ offs, const int* __restrict__ csr_src,
    const int* __restrict__ csr_eid) {
  // we_s: stride-10 layout (feature f, lane-chunk sub, elem j) -> f*160+sub*10+j
  __shared__ float we_s[16 * 160];  // 10 KB, conflict-free reads
  for (int i = threadIdx.x; i < 2048; i += 256) {
    int f = i >> 7, d = i & 127;
    we_s[f * 160 + (d >> 3) * 10 + (d & 7)] = we[i];
  }
  __syncthreads();

  const int lane = threadIdx.x & 63;
  const int wid = threadIdx.x >> 6;
  const int g = lane >> 4, sub = lane & 15;
  const int nid = blockIdx.x * 16 + wid * 4 + g;
  const int d0 = sub * 8;
  const float inv_sqrt_d = 0.08838834764831845f;  // 1/sqrt(128)

  float4 qlo, qhi;
  load8h(qkv + (size_t)nid * 384 + d0, qlo, qhi);
  float4 slo = *(const float4*)(h + (size_t)nid * D + d0);
  float4 shi = *(const float4*)(h + (size_t)nid * D + d0 + 4);
  const float tf = tq[(size_t)nid * 16 + sub];

  const int eb = offs[nid], ee = offs[nid + 1];
  float m = -3.0e38f, den = 0.f, accE = 0.f;
  float4 alo = {0.f, 0.f, 0.f, 0.f}, ahi = {0.f, 0.f, 0.f, 0.f};

  // 2-deep pipeline over this group's edges
  float4 klon = {0,0,0,0}, khin = {0,0,0,0}, vlon = {0,0,0,0}, vhin = {0,0,0,0};
  float eafn = 0.f;
  int p = eb;
  if (p < ee) {
    int src = csr_src[p];
    int eid = csr_eid[p];
    load8h(qkv + (size_t)src * 384 + 128 + d0, klon, khin);
    load8h(qkv + (size_t)src * 384 + 256 + d0, vlon, vhin);
    eafn = edge_attr[(size_t)eid * 16 + sub];
  }
  while (p < ee) {
    float4 klo = klon, khi = khin, vlo = vlon, vhi = vhin;
    float eaf = eafn;
    ++p;
    if (p < ee) {
      int src = csr_src[p];
      int eid = csr_eid[p];
      load8h(qkv + (size_t)src * 384 + 128 + d0, klon, khin);
      load8h(qkv + (size_t)src * 384 + 256 + d0, vlon, vhin);
      eafn = edge_attr[(size_t)eid * 16 + sub];
    }
    float pa = qlo.x * klo.x + qlo.y * klo.y + qlo.z * klo.z + qlo.w * klo.w +
               qhi.x * khi.x + qhi.y * khi.y + qhi.z * khi.z + qhi.w * khi.w +
               eaf * tf;
    #pragma unroll
    for (int off = 8; off > 0; off >>= 1) pa += __shfl_xor(pa, off, 64);
    pa *= inv_sqrt_d;
    float mn = fmaxf(m, pa);
    float esc = __expf(m - mn);
    float ew = __expf(pa - mn);
    den = den * esc + ew;
    alo.x = alo.x * esc + ew * vlo.x;
    alo.y = alo.y * esc + ew * vlo.y;
    alo.z = alo.z * esc + ew * vlo.z;
    alo.w = alo.w * esc + ew * vlo.w;
    ahi.x = ahi.x * esc + ew * vhi.x;
    ahi.y = ahi.y * esc + ew * vhi.y;
    ahi.z = ahi.z * esc + ew * vhi.z;
    ahi.w = ahi.w * esc + ew * vhi.w;
    accE = accE * esc + ew * eaf;
    m = mn;
  }

  if (den > 0.f) {
    float inv = 1.0f / den;
    float4 elo = {0.f, 0.f, 0.f, 0.f}, ehi = {0.f, 0.f, 0.f, 0.f};
    const int gbase = lane & 48;
    const int wb = sub * 10;
    #pragma unroll
    for (int f = 0; f < 16; ++f) {
      float aE = __shfl(accE, gbase + f, 64);
      const float* wr = &we_s[f * 160 + wb];
      float2 w01 = *(const float2*)(wr + 0);
      float2 w23 = *(const float2*)(wr + 2);
      float2 w45 = *(const float2*)(wr + 4);
      float2 w67 = *(const float2*)(wr + 6);
      elo.x += aE * w01.x; elo.y += aE * w01.y; elo.z += aE * w23.x; elo.w += aE * w23.y;
      ehi.x += aE * w45.x; ehi.y += aE * w45.y; ehi.z += aE * w67.x; ehi.w += aE * w67.y;
    }
    slo.x += (alo.x + elo.x) * inv;
    slo.y += (alo.y + elo.y) * inv;
    slo.z += (alo.z + elo.z) * inv;
    slo.w += (alo.w + elo.w) * inv;
    shi.x += (ahi.x + ehi.x) * inv;
    shi.y += (ahi.y + ehi.y) * inv;
    shi.z += (ahi.z + ehi.z) * inv;
    shi.w += (ahi.w + ehi.w) * inv;
  }
  slo.x = fmaxf(slo.x, 0.f); slo.y = fmaxf(slo.y, 0.f);
  slo.z = fmaxf(slo.z, 0.f); slo.w = fmaxf(slo.w, 0.f);
  shi.x = fmaxf(shi.x, 0.f); shi.y = fmaxf(shi.y, 0.f);
  shi.z = fmaxf(shi.z, 0.f); shi.w = fmaxf(shi.w, 0.f);
  *(float4*)(h + (size_t)nid * D + d0) = slo;
  *(float4*)(h + (size_t)nid * D + d0 + 4) = shi;
}

// ---------------- segmented mean-pool (batch sorted) ----------------
__global__ __launch_bounds__(64) void pool_kernel(const float* __restrict__ h,
                                                  const int* __restrict__ batch,
                                                  float* __restrict__ hg,
                                                  float* __restrict__ cnt, int n) {
  int base = blockIdx.x * 128;
  int lane = threadIdx.x;
  float2 acc = {0.f, 0.f};
  float run = 0.f;
  int cur = batch[base];
  for (int i = 0; i < 128; ++i) {
    int node = base + i;
    int g = batch[node];
    if (g != cur) {
      atomicAdd(&hg[(size_t)cur * D + 2 * lane], acc.x);
      atomicAdd(&hg[(size_t)cur * D + 2 * lane + 1], acc.y);
      if (lane == 0) atomicAdd(&cnt[cur], run);
      acc.x = acc.y = 0.f; run = 0.f; cur = g;
    }
    float2 hv = *(const float2*)(h + (size_t)node * D + 2 * lane);
    acc.x += hv.x; acc.y += hv.y; run += 1.f;
  }
  atomicAdd(&hg[(size_t)cur * D + 2 * lane], acc.x);
  atomicAdd(&hg[(size_t)cur * D + 2 * lane + 1], acc.y);
  if (lane == 0) atomicAdd(&cnt[cur], run);
}

// ---------------- head: mean, fc2+relu, fc3 (one wave per graph) ----------------
__global__ __launch_bounds__(256) void head_kernel(const float* __restrict__ hg,
                                                   const float* __restrict__ cnt,
                                                   const float* __restrict__ w2,
                                                   const float* __restrict__ b2,
                                                   const float* __restrict__ w3,
                                                   const float* __restrict__ b3,
                                                   float* __restrict__ out) {
  __shared__ float w2s[128 * 16];
  __shared__ float rowb[4][128];
  for (int i = threadIdx.x; i < (128 * 16) / 4; i += 256)
    ((float4*)w2s)[i] = ((const float4*)w2)[i];
  int wid = threadIdx.x >> 6, lane = threadIdx.x & 63;
  int g = blockIdx.x * 4 + wid;
  float inv = 1.0f / fmaxf(cnt[g], 1.0f);
  rowb[wid][lane] = hg[(size_t)g * D + lane] * inv;
  rowb[wid][lane + 64] = hg[(size_t)g * D + 64 + lane] * inv;
  __syncthreads();
  float t = 0.f;
  if (lane < 16) {
    float a = b2[lane];
    for (int d = 0; d < 128; ++d) a += rowb[wid][d] * w2s[d * 16 + lane];
    t = fmaxf(a, 0.f) * w3[lane];
  }
  #pragma unroll
  for (int off = 8; off > 0; off >>= 1) t += __shfl_xor(t, off, 64);
  if (lane == 0) out[g] = t + b3[0];
}

// ---------------- launch ----------------
extern "C" void kernel_launch(void* const* d_in, const int* in_sizes, int n_in,
                              void* d_out, int out_size, void* d_ws, size_t ws_size,
                              hipStream_t stream) {
  const float* x = (const float*)d_in[0];
  const int* eidx = (const int*)d_in[1];
  const float* eattr = (const float*)d_in[2];
  const int* batch = (const int*)d_in[3];
  const float* fc1_w = (const float*)d_in[4];
  const float* fc1_b = (const float*)d_in[5];
  const float* WQ[3] = {(const float*)d_in[6], (const float*)d_in[15], (const float*)d_in[24]};
  const float* BQ[3] = {(const float*)d_in[7], (const float*)d_in[16], (const float*)d_in[25]};
  const float* WK[3] = {(const float*)d_in[8], (const float*)d_in[17], (const float*)d_in[26]};
  const float* BK[3] = {(const float*)d_in[9], (const float*)d_in[18], (const float*)d_in[27]};
  const float* WV[3] = {(const float*)d_in[10], (const float*)d_in[19], (const float*)d_in[28]};
  const float* BV[3] = {(const float*)d_in[11], (const float*)d_in[20], (const float*)d_in[29]};
  const float* WE[3] = {(const float*)d_in[12], (const float*)d_in[21], (const float*)d_in[30]};
  const float* WS[3] = {(const float*)d_in[13], (const float*)d_in[22], (const float*)d_in[31]};
  const float* BS[3] = {(const float*)d_in[14], (const float*)d_in[23], (const float*)d_in[32]};
  const float* fc2_w = (const float*)d_in[33];
  const float* fc2_b = (const float*)d_in[34];
  const float* fc3_w = (const float*)d_in[35];
  const float* fc3_b = (const float*)d_in[36];

  const int N = in_sizes[0] / 64;
  const int E = in_sizes[1] / 2;
  const int G = out_size;  // DIM_OUT = 1
  const int* srcs = eidx;
  const int* dsts = eidx + E;
  const size_t ND = (size_t)N * D;

  char* base = (char*)d_ws;
  size_t off = 0;
  auto alloc = [&](size_t bytes) {
    void* p = base + off;
    off = (off + bytes + 255) & ~(size_t)255;
    return p;
  };
  // zeroed region first: hg, cnt, counts, cursor
  float* hg = (float*)alloc((size_t)G * D * 4);
  float* cntf = (float*)alloc((size_t)G * 4);
  int* counts = (int*)alloc((size_t)N * 4);
  int* cursor = (int*)alloc((size_t)N * 4);
  size_t zero_bytes = off;
  int* incl = (int*)alloc((size_t)N * 4);
  int* offs = (int*)alloc((size_t)(N + 4) * 4);
  int* bsum = (int*)alloc(512 * 4);
  int* csr_src = (int*)alloc((size_t)E * 4);
  int* csr_eid = (int*)alloc((size_t)E * 4);
  float* h = (float*)alloc(ND * 4);
  __half* qkv = (__half*)alloc((size_t)N * 384 * 2);
  float* qt = (float*)alloc((size_t)N * 16 * 4);
  __half* Wt[3];
  float* bc[3];
  for (int l = 0; l < 3; ++l) {
    Wt[l] = (__half*)alloc(528 * 128 * 2);  // q|k|v|s (512) + Wqe (16)
    bc[l] = (float*)alloc(544 * 4);         // 512 biases + 16 bqe
  }
  __half* fc1t = (__half*)alloc(128 * 64 * 2);
  if (off > ws_size) return;  // ws too small (diagnostic: stub-identical absmax)

  hipMemsetAsync(hg, 0, zero_bytes, stream);

  // weight prep: transpose+fp16 (q|k|v|s per layer), Wqe/bqe, bias concat, fc1
  for (int l = 0; l < 3; ++l) {
    convw_kernel<<<64, 256, 0, stream>>>(WQ[l], Wt[l] + 0 * 16384, 128, 128);
    convw_kernel<<<64, 256, 0, stream>>>(WK[l], Wt[l] + 1 * 16384, 128, 128);
    convw_kernel<<<64, 256, 0, stream>>>(WV[l], Wt[l] + 2 * 16384, 128, 128);
    convw_kernel<<<64, 256, 0, stream>>>(WS[l], Wt[l] + 3 * 16384, 128, 128);
    convwe_kernel<<<9, 256, 0, stream>>>(WE[l], WQ[l], BQ[l],
                                         Wt[l] + 4 * 16384, bc[l] + 512);
    bcat_kernel<<<2, 256, 0, stream>>>(BQ[l], BK[l], BV[l], BS[l], bc[l]);
  }
  convw_kernel<<<32, 256, 0, stream>>>(fc1_w, fc1t, 128, 64);

  // CSR build (deterministic after sort)
  hist_kernel<<<E / 256, 256, 0, stream>>>(dsts, counts, E);
  scan_a_kernel<<<N / 256, 256, 0, stream>>>(counts, incl, bsum);
  scan_b_kernel<<<1, 512, 0, stream>>>(bsum);
  scan_c_kernel<<<N / 256, 256, 0, stream>>>(incl, counts, bsum, offs, N, E);
  scatter_kernel<<<E / 256, 256, 0, stream>>>(srcs, dsts, offs, cursor, csr_src, csr_eid, E);
  sort_kernel<<<N / 256, 256, 0, stream>>>(offs, csr_eid, csr_src, N);

  // fc1: h = x @ fc1_w + fc1_b  (MFMA, K=64, 128 cols)
  mfma_gemm_kernel<64, 8, false><<<N / 64, 256, 0, stream>>>(
      x, fc1t, fc1_b, nullptr, h, nullptr);

  // 3 transformer-conv layers
  for (int l = 0; l < 3; ++l) {
    mfma_gemm_kernel<128, 32, true><<<N / 64, 256, 0, stream>>>(
        h, Wt[l], bc[l], qkv, h, qt);
    node_kernel<<<N / 16, 256, 0, stream>>>(qkv, h, eattr, WE[l], qt,
                                            offs, csr_src, csr_eid);
  }

  // mean pool + head
  pool_kernel<<<N / 128, 64, 0, stream>>>(h, batch, hg, cntf, N);
  head_kernel<<<G / 4, 256, 0, stream>>>(hg, cntf, fc2_w, fc2_b, fc3_w, fc3_b, (float*)d_out);
}

// Round 13
// 598.444 us; speedup vs baseline: 2.8299x; 1.0566x over previous
//
#include <hip/hip_runtime.h>
#include <hip/hip_fp16.h>

// TFNN: 3-layer TransformerConv GNN.
// Round 13: round-10 node layout (separate q/k/v — best measured) + stride-10
// we_s (conflict fix) + ALL weight-prep fused into one kernel (19 launches -> 1).

#define D 128

typedef _Float16 half8 __attribute__((ext_vector_type(8)));
typedef float f32x4 __attribute__((ext_vector_type(4)));

// ---------------- CSR build ----------------
__global__ __launch_bounds__(256) void hist_kernel(const int* __restrict__ dst,
                                                   int* __restrict__ counts, int e) {
  int i = blockIdx.x * 256 + threadIdx.x;
  if (i < e) atomicAdd(&counts[dst[i]], 1);
}

__global__ __launch_bounds__(256) void scan_a_kernel(const int* __restrict__ counts,
                                                     int* __restrict__ incl,
                                                     int* __restrict__ bsum) {
  int gid = blockIdx.x * 256 + threadIdx.x;
  int lane = threadIdx.x & 63, wid = threadIdx.x >> 6;
  int v = counts[gid];
  int s = v;
  #pragma unroll
  for (int off = 1; off < 64; off <<= 1) {
    int t = __shfl_up(s, off, 64);
    if (lane >= off) s += t;
  }
  __shared__ int wsum[4];
  if (lane == 63) wsum[wid] = s;
  __syncthreads();
  #pragma unroll
  for (int w = 0; w < 3; ++w)
    if (wid > w) s += wsum[w];
  incl[gid] = s;
  if (threadIdx.x == 255) bsum[blockIdx.x] = s;
}

__global__ __launch_bounds__(512) void scan_b_kernel(int* __restrict__ bs) {
  int tid = threadIdx.x;
  int lane = tid & 63, wid = tid >> 6;
  int v = bs[tid];
  int s = v;
  #pragma unroll
  for (int off = 1; off < 64; off <<= 1) {
    int t = __shfl_up(s, off, 64);
    if (lane >= off) s += t;
  }
  __shared__ int wsum[8];
  if (lane == 63) wsum[wid] = s;
  __syncthreads();
  #pragma unroll
  for (int w = 0; w < 7; ++w)
    if (wid > w) s += wsum[w];
  bs[tid] = s - v;  // exclusive block prefix
}

__global__ __launch_bounds__(256) void scan_c_kernel(const int* __restrict__ incl,
                                                     const int* __restrict__ counts,
                                                     const int* __restrict__ bsum,
                                                     int* __restrict__ offs, int n, int e) {
  int gid = blockIdx.x * 256 + threadIdx.x;
  if (gid < n) offs[gid] = incl[gid] - counts[gid] + bsum[blockIdx.x];
  if (gid == 0) offs[n] = e;
}

__global__ __launch_bounds__(256) void scatter_kernel(const int* __restrict__ srcs,
                                                      const int* __restrict__ dsts,
                                                      const int* __restrict__ offs,
                                                      int* __restrict__ cursor,
                                                      int* __restrict__ csr_src,
                                                      int* __restrict__ csr_eid, int e) {
  int i = blockIdx.x * 256 + threadIdx.x;
  if (i >= e) return;
  int d = dsts[i];
  int slot = atomicAdd(&cursor[d], 1);
  int p = offs[d] + slot;
  csr_src[p] = srcs[i];
  csr_eid[p] = i;
}

// deterministic order: sort each node's incoming edge list by edge id
__global__ __launch_bounds__(256) void sort_kernel(const int* __restrict__ offs,
                                                   int* __restrict__ eid,
                                                   int* __restrict__ srcs, int n) {
  int i = blockIdx.x * 256 + threadIdx.x;
  if (i >= n) return;
  int b = offs[i], e = offs[i + 1];
  for (int p = b + 1; p < e; ++p) {
    int ke = eid[p], ks = srcs[p];
    int q = p - 1;
    while (q >= b && eid[q] > ke) {
      eid[q + 1] = eid[q]; srcs[q + 1] = srcs[q]; --q;
    }
    eid[q + 1] = ke; srcs[q + 1] = ks;
  }
}

// ---------------- fused weight prep (one launch) ----------------
// blocks 0..767   : 12x transpose+fp16 of 128x128 (WQ/WK/WV/WS x 3 layers)
// blocks 768..799 : fc1 transpose (128 cols x 64 K)
// blocks 800..826 : convwe x3 (Wqe = we@Wq^T fp16, bqe = we@bq fp32)
// blocks 827..832 : bias concat x3 (bq|bk|bv|bs)
struct PrepArgs {
  const float* W[12];   // layer-major: WQ0,WK0,WV0,WS0, WQ1,...
  const float* WE[3];
  const float* BQ[3];
  const float* BK[3];
  const float* BV[3];
  const float* BS[3];
  const float* fc1w;
  __half* Wt[3];
  float* bc[3];
  __half* fc1t;
};

__global__ __launch_bounds__(256) void prep_kernel(PrepArgs a) {
  int b = blockIdx.x, tid = threadIdx.x;
  if (b < 768) {
    int m = b >> 6;                    // matrix id 0..11
    int l = m >> 2, s = m & 3;
    int idx = ((b & 63) << 8) | tid;   // 0..16383
    int n = idx >> 7, kk = idx & 127;
    a.Wt[l][s * 16384 + idx] = __float2half(a.W[m][(size_t)kk * 128 + n]);
  } else if (b < 800) {
    int idx = ((b - 768) << 8) | tid;  // 0..8191
    int n = idx >> 6, kk = idx & 63;
    a.fc1t[idx] = __float2half(a.fc1w[(size_t)kk * 128 + n]);
  } else if (b < 827) {
    int l = (b - 800) / 9;
    int idx = ((b - 800) % 9) * 256 + tid;
    if (idx < 2048) {
      int f = idx >> 7, kk = idx & 127;
      float s = 0.f;
      for (int d = 0; d < 128; ++d)
        s += a.WE[l][f * 128 + d] * a.W[l * 4][(size_t)kk * 128 + d];
      a.Wt[l][4 * 16384 + f * 128 + kk] = __float2half(s);
    } else if (idx < 2064) {
      int f = idx - 2048;
      float s = 0.f;
      for (int d = 0; d < 128; ++d) s += a.WE[l][f * 128 + d] * a.BQ[l][d];
      a.bc[l][512 + f] = s;
    }
  } else {
    int l = (b - 827) >> 1;
    int j = ((b - 827) & 1) * 256 + tid;
    const float* src = (j < 128) ? a.BQ[l] : (j < 256) ? a.BK[l]
                     : (j < 384) ? a.BV[l] : a.BS[l];
    a.bc[l][j] = src[j & 127];
  }
}

// ---------------- typed stores / loads ----------------
__device__ inline void store4h(__half* p, float4 v) {
  __half2 h01 = __floats2half2_rn(v.x, v.y);
  __half2 h23 = __floats2half2_rn(v.z, v.w);
  uint2 u;
  u.x = *(unsigned int*)&h01;
  u.y = *(unsigned int*)&h23;
  *(uint2*)p = u;
}

__device__ inline void load8h(const __half* p, float4& lo, float4& hi) {
  uint4 u = *(const uint4*)p;
  float2 a = __half22float2(*(__half2*)&u.x);
  float2 b = __half22float2(*(__half2*)&u.y);
  float2 c = __half22float2(*(__half2*)&u.z);
  float2 d = __half22float2(*(__half2*)&u.w);
  lo = make_float4(a.x, a.y, b.x, b.y);
  hi = make_float4(c.x, c.y, d.x, d.y);
}

// ---------------- MFMA GEMM (LDS-staged W chunks + optional 16-col t-tile) ----------------
// in [Nrows][K] fp32; Wt [(NCT*16 + (QKVS?16:0))][K] fp16; bias matching fp32.
// QKVS: cols 0-127->oq, 128-255->ok, 256-383->ov (fp16), 384-511->os (fp32, may
// alias `in`: each lane fully reads its own row before any store), cols 512-527
// -> qt fp32 [Nrows][16] (t = we@q per node).
template <int K, int NCT, bool QKVS>
__global__ __launch_bounds__(256) void mfma_gemm_kernel(
    const float* in, const __half* __restrict__ Wt, const float* __restrict__ bias,
    __half* __restrict__ oq, __half* __restrict__ ok, __half* __restrict__ ov,
    float* os, float* __restrict__ qt) {
  constexpr int WST = K + 8;  // Wc row stride in halfs; (K+8)*2 bytes % 16 == 0
  __shared__ alignas(16) __half Wc[128 * WST];  // current 128-col W chunk
  const int tid = threadIdx.x;
  const int w = tid >> 6, l = tid & 63;
  const int lo = l & 15, hi = l >> 4;
  const size_t row = (size_t)blockIdx.x * 64 + w * 16 + lo;

  // A-side (h) fragments: 8 consecutive fp32 of own row per k-step, cvt fp16
  half8 af[K / 32];
  #pragma unroll
  for (int s = 0; s < K / 32; ++s) {
    const float* sp = in + row * K + s * 32 + hi * 8;
    float4 f0 = *(const float4*)sp;
    float4 f1 = *(const float4*)(sp + 4);
    half8 a;
    a[0] = (_Float16)f0.x; a[1] = (_Float16)f0.y; a[2] = (_Float16)f0.z; a[3] = (_Float16)f0.w;
    a[4] = (_Float16)f1.x; a[5] = (_Float16)f1.y; a[6] = (_Float16)f1.z; a[7] = (_Float16)f1.w;
    af[s] = a;
  }

  // chunk loop: 128 output cols per chunk, W chunk staged in LDS
  #pragma unroll 1
  for (int ch = 0; ch < NCT / 8; ++ch) {
    __syncthreads();  // protect Wc reuse across chunks
    #pragma unroll
    for (int i = 0; i < 128 * K / 8 / 256; ++i) {
      int idx = i * 256 + tid;
      int col = idx / (K / 8), kk = (idx % (K / 8)) * 8;
      *(uint4*)&Wc[col * WST + kk] =
          *(const uint4*)(Wt + (size_t)(ch * 128 + col) * K + kk);
    }
    __syncthreads();

    #pragma unroll
    for (int t = 0; t < 8; ++t) {
      f32x4 c = {0.f, 0.f, 0.f, 0.f};
      #pragma unroll
      for (int s = 0; s < K / 32; ++s) {
        half8 bf = *(const half8*)&Wc[(t * 16 + lo) * WST + s * 32 + hi * 8];
        c = __builtin_amdgcn_mfma_f32_16x16x32_f16(bf, af[s], c, 0, 0, 0);
      }
      const int col0 = ch * 128 + t * 16 + hi * 4;
      float4 b4 = *(const float4*)(bias + col0);
      float4 o;
      o.x = c[0] + b4.x; o.y = c[1] + b4.y; o.z = c[2] + b4.z; o.w = c[3] + b4.w;
      if (QKVS) {
        const int mid = col0 >> 7, cc = col0 & 127;
        if (mid == 0)      store4h(oq + row * 128 + cc, o);
        else if (mid == 1) store4h(ok + row * 128 + cc, o);
        else if (mid == 2) store4h(ov + row * 128 + cc, o);
        else               *(float4*)(os + row * 128 + cc) = o;
      } else {
        *(float4*)(os + row * 128 + col0) = o;
      }
    }
  }

  // t-tile: 16 extra cols (Wqe rows 512..527) -> qt[row][0..15]
  if constexpr (QKVS) {
    __syncthreads();  // last chunk's MFMAs done reading Wc
    {
      int col = tid >> 4;          // K/8 == 16 -> exactly 256 vec4 copies
      int kk = (tid & 15) * 8;
      *(uint4*)&Wc[col * WST + kk] =
          *(const uint4*)(Wt + (size_t)(512 + col) * K + kk);
    }
    __syncthreads();
    f32x4 c = {0.f, 0.f, 0.f, 0.f};
    #pragma unroll
    for (int s = 0; s < K / 32; ++s) {
      half8 bf = *(const half8*)&Wc[lo * WST + s * 32 + hi * 8];
      c = __builtin_amdgcn_mfma_f32_16x16x32_f16(bf, af[s], c, 0, 0, 0);
    }
    float4 b4 = *(const float4*)(bias + 512 + hi * 4);
    float4 o;
    o.x = c[0] + b4.x; o.y = c[1] + b4.y; o.z = c[2] + b4.z; o.w = c[3] + b4.w;
    *(float4*)(qt + row * 16 + hi * 4) = o;
  }
}

// ---------------- node-centric transformer conv: 4 nodes per wave ----------------
// 16-lane group per node (sequential node ids -> wave reads 4 consecutive
// rows), 8 dims/lane. h holds s on entry; writes relu(s + (accV+accE@we)/den).
__global__ __launch_bounds__(256) void node_kernel(
    const __half* __restrict__ q, const __half* __restrict__ k, const __half* __restrict__ v,
    float* __restrict__ h, const float* __restrict__ edge_attr,
    const float* __restrict__ we, const float* __restrict__ tq,
    const int* __restrict__ offs, const int* __restrict__ csr_src,
    const int* __restrict__ csr_eid) {
  // we_s: stride-10 layout (feature f, lane-chunk sub, elem j) -> f*160+sub*10+j
  __shared__ float we_s[16 * 160];  // 10 KB, conflict-free reads
  for (int i = threadIdx.x; i < 2048; i += 256) {
    int f = i >> 7, d = i & 127;
    we_s[f * 160 + (d >> 3) * 10 + (d & 7)] = we[i];
  }
  __syncthreads();

  const int lane = threadIdx.x & 63;
  const int wid = threadIdx.x >> 6;
  const int g = lane >> 4, sub = lane & 15;
  const int nid = blockIdx.x * 16 + wid * 4 + g;
  const int d0 = sub * 8;
  const float inv_sqrt_d = 0.08838834764831845f;  // 1/sqrt(128)

  float4 qlo, qhi;
  load8h(q + (size_t)nid * D + d0, qlo, qhi);
  float4 slo = *(const float4*)(h + (size_t)nid * D + d0);
  float4 shi = *(const float4*)(h + (size_t)nid * D + d0 + 4);
  const float tf = tq[(size_t)nid * 16 + sub];

  const int eb = offs[nid], ee = offs[nid + 1];
  float m = -3.0e38f, den = 0.f, accE = 0.f;
  float4 alo = {0.f, 0.f, 0.f, 0.f}, ahi = {0.f, 0.f, 0.f, 0.f};

  // 2-deep pipeline over this group's edges
  float4 klon = {0,0,0,0}, khin = {0,0,0,0}, vlon = {0,0,0,0}, vhin = {0,0,0,0};
  float eafn = 0.f;
  int p = eb;
  if (p < ee) {
    int src = csr_src[p];
    int eid = csr_eid[p];
    load8h(k + (size_t)src * D + d0, klon, khin);
    load8h(v + (size_t)src * D + d0, vlon, vhin);
    eafn = edge_attr[(size_t)eid * 16 + sub];
  }
  while (p < ee) {
    float4 klo = klon, khi = khin, vlo = vlon, vhi = vhin;
    float eaf = eafn;
    ++p;
    if (p < ee) {
      int src = csr_src[p];
      int eid = csr_eid[p];
      load8h(k + (size_t)src * D + d0, klon, khin);
      load8h(v + (size_t)src * D + d0, vlon, vhin);
      eafn = edge_attr[(size_t)eid * 16 + sub];
    }
    float pa = qlo.x * klo.x + qlo.y * klo.y + qlo.z * klo.z + qlo.w * klo.w +
               qhi.x * khi.x + qhi.y * khi.y + qhi.z * khi.z + qhi.w * khi.w +
               eaf * tf;
    #pragma unroll
    for (int off = 8; off > 0; off >>= 1) pa += __shfl_xor(pa, off, 64);
    pa *= inv_sqrt_d;
    float mn = fmaxf(m, pa);
    float esc = __expf(m - mn);
    float ew = __expf(pa - mn);
    den = den * esc + ew;
    alo.x = alo.x * esc + ew * vlo.x;
    alo.y = alo.y * esc + ew * vlo.y;
    alo.z = alo.z * esc + ew * vlo.z;
    alo.w = alo.w * esc + ew * vlo.w;
    ahi.x = ahi.x * esc + ew * vhi.x;
    ahi.y = ahi.y * esc + ew * vhi.y;
    ahi.z = ahi.z * esc + ew * vhi.z;
    ahi.w = ahi.w * esc + ew * vhi.w;
    accE = accE * esc + ew * eaf;
    m = mn;
  }

  if (den > 0.f) {
    float inv = 1.0f / den;
    float4 elo = {0.f, 0.f, 0.f, 0.f}, ehi = {0.f, 0.f, 0.f, 0.f};
    const int gbase = lane & 48;
    const int wb = sub * 10;
    #pragma unroll
    for (int f = 0; f < 16; ++f) {
      float aE = __shfl(accE, gbase + f, 64);
      const float* wr = &we_s[f * 160 + wb];
      float2 w01 = *(const float2*)(wr + 0);
      float2 w23 = *(const float2*)(wr + 2);
      float2 w45 = *(const float2*)(wr + 4);
      float2 w67 = *(const float2*)(wr + 6);
      elo.x += aE * w01.x; elo.y += aE * w01.y; elo.z += aE * w23.x; elo.w += aE * w23.y;
      ehi.x += aE * w45.x; ehi.y += aE * w45.y; ehi.z += aE * w67.x; ehi.w += aE * w67.y;
    }
    slo.x += (alo.x + elo.x) * inv;
    slo.y += (alo.y + elo.y) * inv;
    slo.z += (alo.z + elo.z) * inv;
    slo.w += (alo.w + elo.w) * inv;
    shi.x += (ahi.x + ehi.x) * inv;
    shi.y += (ahi.y + ehi.y) * inv;
    shi.z += (ahi.z + ehi.z) * inv;
    shi.w += (ahi.w + ehi.w) * inv;
  }
  slo.x = fmaxf(slo.x, 0.f); slo.y = fmaxf(slo.y, 0.f);
  slo.z = fmaxf(slo.z, 0.f); slo.w = fmaxf(slo.w, 0.f);
  shi.x = fmaxf(shi.x, 0.f); shi.y = fmaxf(shi.y, 0.f);
  shi.z = fmaxf(shi.z, 0.f); shi.w = fmaxf(shi.w, 0.f);
  *(float4*)(h + (size_t)nid * D + d0) = slo;
  *(float4*)(h + (size_t)nid * D + d0 + 4) = shi;
}

// ---------------- segmented mean-pool (batch sorted) ----------------
__global__ __launch_bounds__(64) void pool_kernel(const float* __restrict__ h,
                                                  const int* __restrict__ batch,
                                                  float* __restrict__ hg,
                                                  float* __restrict__ cnt, int n) {
  int base = blockIdx.x * 128;
  int lane = threadIdx.x;
  float2 acc = {0.f, 0.f};
  float run = 0.f;
  int cur = batch[base];
  for (int i = 0; i < 128; ++i) {
    int node = base + i;
    int g = batch[node];
    if (g != cur) {
      atomicAdd(&hg[(size_t)cur * D + 2 * lane], acc.x);
      atomicAdd(&hg[(size_t)cur * D + 2 * lane + 1], acc.y);
      if (lane == 0) atomicAdd(&cnt[cur], run);
      acc.x = acc.y = 0.f; run = 0.f; cur = g;
    }
    float2 hv = *(const float2*)(h + (size_t)node * D + 2 * lane);
    acc.x += hv.x; acc.y += hv.y; run += 1.f;
  }
  atomicAdd(&hg[(size_t)cur * D + 2 * lane], acc.x);
  atomicAdd(&hg[(size_t)cur * D + 2 * lane + 1], acc.y);
  if (lane == 0) atomicAdd(&cnt[cur], run);
}

// ---------------- head: mean, fc2+relu, fc3 (one wave per graph) ----------------
__global__ __launch_bounds__(256) void head_kernel(const float* __restrict__ hg,
                                                   const float* __restrict__ cnt,
                                                   const float* __restrict__ w2,
                                                   const float* __restrict__ b2,
                                                   const float* __restrict__ w3,
                                                   const float* __restrict__ b3,
                                                   float* __restrict__ out) {
  __shared__ float w2s[128 * 16];
  __shared__ float rowb[4][128];
  for (int i = threadIdx.x; i < (128 * 16) / 4; i += 256)
    ((float4*)w2s)[i] = ((const float4*)w2)[i];
  int wid = threadIdx.x >> 6, lane = threadIdx.x & 63;
  int g = blockIdx.x * 4 + wid;
  float inv = 1.0f / fmaxf(cnt[g], 1.0f);
  rowb[wid][lane] = hg[(size_t)g * D + lane] * inv;
  rowb[wid][lane + 64] = hg[(size_t)g * D + 64 + lane] * inv;
  __syncthreads();
  float t = 0.f;
  if (lane < 16) {
    float a = b2[lane];
    for (int d = 0; d < 128; ++d) a += rowb[wid][d] * w2s[d * 16 + lane];
    t = fmaxf(a, 0.f) * w3[lane];
  }
  #pragma unroll
  for (int off = 8; off > 0; off >>= 1) t += __shfl_xor(t, off, 64);
  if (lane == 0) out[g] = t + b3[0];
}

// ---------------- launch ----------------
extern "C" void kernel_launch(void* const* d_in, const int* in_sizes, int n_in,
                              void* d_out, int out_size, void* d_ws, size_t ws_size,
                              hipStream_t stream) {
  const float* x = (const float*)d_in[0];
  const int* eidx = (const int*)d_in[1];
  const float* eattr = (const float*)d_in[2];
  const int* batch = (const int*)d_in[3];
  const float* fc1_w = (const float*)d_in[4];
  const float* fc1_b = (const float*)d_in[5];
  const float* WQ[3] = {(const float*)d_in[6], (const float*)d_in[15], (const float*)d_in[24]};
  const float* BQ[3] = {(const float*)d_in[7], (const float*)d_in[16], (const float*)d_in[25]};
  const float* WK[3] = {(const float*)d_in[8], (const float*)d_in[17], (const float*)d_in[26]};
  const float* BK[3] = {(const float*)d_in[9], (const float*)d_in[18], (const float*)d_in[27]};
  const float* WV[3] = {(const float*)d_in[10], (const float*)d_in[19], (const float*)d_in[28]};
  const float* BV[3] = {(const float*)d_in[11], (const float*)d_in[20], (const float*)d_in[29]};
  const float* WE[3] = {(const float*)d_in[12], (const float*)d_in[21], (const float*)d_in[30]};
  const float* WS[3] = {(const float*)d_in[13], (const float*)d_in[22], (const float*)d_in[31]};
  const float* BS[3] = {(const float*)d_in[14], (const float*)d_in[23], (const float*)d_in[32]};
  const float* fc2_w = (const float*)d_in[33];
  const float* fc2_b = (const float*)d_in[34];
  const float* fc3_w = (const float*)d_in[35];
  const float* fc3_b = (const float*)d_in[36];

  const int N = in_sizes[0] / 64;
  const int E = in_sizes[1] / 2;
  const int G = out_size;  // DIM_OUT = 1
  const int* srcs = eidx;
  const int* dsts = eidx + E;
  const size_t ND = (size_t)N * D;

  char* base = (char*)d_ws;
  size_t off = 0;
  auto alloc = [&](size_t bytes) {
    void* p = base + off;
    off = (off + bytes + 255) & ~(size_t)255;
    return p;
  };
  // zeroed region first: hg, cnt, counts, cursor
  float* hg = (float*)alloc((size_t)G * D * 4);
  float* cntf = (float*)alloc((size_t)G * 4);
  int* counts = (int*)alloc((size_t)N * 4);
  int* cursor = (int*)alloc((size_t)N * 4);
  size_t zero_bytes = off;
  int* incl = (int*)alloc((size_t)N * 4);
  int* offs = (int*)alloc((size_t)(N + 4) * 4);
  int* bsum = (int*)alloc(512 * 4);
  int* csr_src = (int*)alloc((size_t)E * 4);
  int* csr_eid = (int*)alloc((size_t)E * 4);
  float* h = (float*)alloc(ND * 4);
  __half* q = (__half*)alloc(ND * 2);
  __half* k = (__half*)alloc(ND * 2);
  __half* v = (__half*)alloc(ND * 2);
  float* qt = (float*)alloc((size_t)N * 16 * 4);
  __half* Wt[3];
  float* bc[3];
  for (int l = 0; l < 3; ++l) {
    Wt[l] = (__half*)alloc(528 * 128 * 2);  // q|k|v|s (512) + Wqe (16)
    bc[l] = (float*)alloc(544 * 4);         // 512 biases + 16 bqe
  }
  __half* fc1t = (__half*)alloc(128 * 64 * 2);
  if (off > ws_size) return;  // ws too small (diagnostic: stub-identical absmax)

  hipMemsetAsync(hg, 0, zero_bytes, stream);

  // fused weight prep (one launch)
  PrepArgs pa;
  for (int l = 0; l < 3; ++l) {
    pa.W[l * 4 + 0] = WQ[l];
    pa.W[l * 4 + 1] = WK[l];
    pa.W[l * 4 + 2] = WV[l];
    pa.W[l * 4 + 3] = WS[l];
    pa.WE[l] = WE[l];
    pa.BQ[l] = BQ[l]; pa.BK[l] = BK[l]; pa.BV[l] = BV[l]; pa.BS[l] = BS[l];
    pa.Wt[l] = Wt[l]; pa.bc[l] = bc[l];
  }
  pa.fc1w = fc1_w;
  pa.fc1t = fc1t;
  prep_kernel<<<833, 256, 0, stream>>>(pa);

  // CSR build (deterministic after sort)
  hist_kernel<<<E / 256, 256, 0, stream>>>(dsts, counts, E);
  scan_a_kernel<<<N / 256, 256, 0, stream>>>(counts, incl, bsum);
  scan_b_kernel<<<1, 512, 0, stream>>>(bsum);
  scan_c_kernel<<<N / 256, 256, 0, stream>>>(incl, counts, bsum, offs, N, E);
  scatter_kernel<<<E / 256, 256, 0, stream>>>(srcs, dsts, offs, cursor, csr_src, csr_eid, E);
  sort_kernel<<<N / 256, 256, 0, stream>>>(offs, csr_eid, csr_src, N);

  // fc1: h = x @ fc1_w + fc1_b  (MFMA, K=64, 128 cols)
  mfma_gemm_kernel<64, 8, false><<<N / 64, 256, 0, stream>>>(
      x, fc1t, fc1_b, nullptr, nullptr, nullptr, h, nullptr);

  // 3 transformer-conv layers
  for (int l = 0; l < 3; ++l) {
    mfma_gemm_kernel<128, 32, true><<<N / 64, 256, 0, stream>>>(
        h, Wt[l], bc[l], q, k, v, h, qt);
    node_kernel<<<N / 16, 256, 0, stream>>>(q, k, v, h, eattr, WE[l], qt,
                                            offs, csr_src, csr_eid);
  }

  // mean pool + head
  pool_kernel<<<N / 128, 64, 0, stream>>>(h, batch, hg, cntf, N);
  head_kernel<<<G / 4, 256, 0, stream>>>(hg, cntf, fc2_w, fc2_b, fc3_w, fc3_b, (float*)d_out);
}

// Round 14
// 532.878 us; speedup vs baseline: 3.1781x; 1.1230x over previous
//
#include <hip/hip_runtime.h>
#include <hip/hip_fp16.h>

// TFNN: 3-layer TransformerConv GNN.
// Round 14: h stored fp16 end-to-end (GEMM A-side loads halfs directly, no cvt;
// s/h traffic halves). Structure otherwise = round 13.

#define D 128

typedef _Float16 half8 __attribute__((ext_vector_type(8)));
typedef float f32x4 __attribute__((ext_vector_type(4)));

// ---------------- CSR build ----------------
__global__ __launch_bounds__(256) void hist_kernel(const int* __restrict__ dst,
                                                   int* __restrict__ counts, int e) {
  int i = blockIdx.x * 256 + threadIdx.x;
  if (i < e) atomicAdd(&counts[dst[i]], 1);
}

__global__ __launch_bounds__(256) void scan_a_kernel(const int* __restrict__ counts,
                                                     int* __restrict__ incl,
                                                     int* __restrict__ bsum) {
  int gid = blockIdx.x * 256 + threadIdx.x;
  int lane = threadIdx.x & 63, wid = threadIdx.x >> 6;
  int v = counts[gid];
  int s = v;
  #pragma unroll
  for (int off = 1; off < 64; off <<= 1) {
    int t = __shfl_up(s, off, 64);
    if (lane >= off) s += t;
  }
  __shared__ int wsum[4];
  if (lane == 63) wsum[wid] = s;
  __syncthreads();
  #pragma unroll
  for (int w = 0; w < 3; ++w)
    if (wid > w) s += wsum[w];
  incl[gid] = s;
  if (threadIdx.x == 255) bsum[blockIdx.x] = s;
}

__global__ __launch_bounds__(512) void scan_b_kernel(int* __restrict__ bs) {
  int tid = threadIdx.x;
  int lane = tid & 63, wid = tid >> 6;
  int v = bs[tid];
  int s = v;
  #pragma unroll
  for (int off = 1; off < 64; off <<= 1) {
    int t = __shfl_up(s, off, 64);
    if (lane >= off) s += t;
  }
  __shared__ int wsum[8];
  if (lane == 63) wsum[wid] = s;
  __syncthreads();
  #pragma unroll
  for (int w = 0; w < 7; ++w)
    if (wid > w) s += wsum[w];
  bs[tid] = s - v;  // exclusive block prefix
}

__global__ __launch_bounds__(256) void scan_c_kernel(const int* __restrict__ incl,
                                                     const int* __restrict__ counts,
                                                     const int* __restrict__ bsum,
                                                     int* __restrict__ offs, int n, int e) {
  int gid = blockIdx.x * 256 + threadIdx.x;
  if (gid < n) offs[gid] = incl[gid] - counts[gid] + bsum[blockIdx.x];
  if (gid == 0) offs[n] = e;
}

__global__ __launch_bounds__(256) void scatter_kernel(const int* __restrict__ srcs,
                                                      const int* __restrict__ dsts,
                                                      const int* __restrict__ offs,
                                                      int* __restrict__ cursor,
                                                      int* __restrict__ csr_src,
                                                      int* __restrict__ csr_eid, int e) {
  int i = blockIdx.x * 256 + threadIdx.x;
  if (i >= e) return;
  int d = dsts[i];
  int slot = atomicAdd(&cursor[d], 1);
  int p = offs[d] + slot;
  csr_src[p] = srcs[i];
  csr_eid[p] = i;
}

// deterministic order: sort each node's incoming edge list by edge id
__global__ __launch_bounds__(256) void sort_kernel(const int* __restrict__ offs,
                                                   int* __restrict__ eid,
                                                   int* __restrict__ srcs, int n) {
  int i = blockIdx.x * 256 + threadIdx.x;
  if (i >= n) return;
  int b = offs[i], e = offs[i + 1];
  for (int p = b + 1; p < e; ++p) {
    int ke = eid[p], ks = srcs[p];
    int q = p - 1;
    while (q >= b && eid[q] > ke) {
      eid[q + 1] = eid[q]; srcs[q + 1] = srcs[q]; --q;
    }
    eid[q + 1] = ke; srcs[q + 1] = ks;
  }
}

// ---------------- fused weight prep (one launch) ----------------
// blocks 0..767   : 12x transpose+fp16 of 128x128 (WQ/WK/WV/WS x 3 layers)
// blocks 768..799 : fc1 transpose (128 cols x 64 K)
// blocks 800..826 : convwe x3 (Wqe = we@Wq^T fp16, bqe = we@bq fp32)
// blocks 827..832 : bias concat x3 (bq|bk|bv|bs)
struct PrepArgs {
  const float* W[12];   // layer-major: WQ0,WK0,WV0,WS0, WQ1,...
  const float* WE[3];
  const float* BQ[3];
  const float* BK[3];
  const float* BV[3];
  const float* BS[3];
  const float* fc1w;
  __half* Wt[3];
  float* bc[3];
  __half* fc1t;
};

__global__ __launch_bounds__(256) void prep_kernel(PrepArgs a) {
  int b = blockIdx.x, tid = threadIdx.x;
  if (b < 768) {
    int m = b >> 6;                    // matrix id 0..11
    int l = m >> 2, s = m & 3;
    int idx = ((b & 63) << 8) | tid;   // 0..16383
    int n = idx >> 7, kk = idx & 127;
    a.Wt[l][s * 16384 + idx] = __float2half(a.W[m][(size_t)kk * 128 + n]);
  } else if (b < 800) {
    int idx = ((b - 768) << 8) | tid;  // 0..8191
    int n = idx >> 6, kk = idx & 63;
    a.fc1t[idx] = __float2half(a.fc1w[(size_t)kk * 128 + n]);
  } else if (b < 827) {
    int l = (b - 800) / 9;
    int idx = ((b - 800) % 9) * 256 + tid;
    if (idx < 2048) {
      int f = idx >> 7, kk = idx & 127;
      float s = 0.f;
      for (int d = 0; d < 128; ++d)
        s += a.WE[l][f * 128 + d] * a.W[l * 4][(size_t)kk * 128 + d];
      a.Wt[l][4 * 16384 + f * 128 + kk] = __float2half(s);
    } else if (idx < 2064) {
      int f = idx - 2048;
      float s = 0.f;
      for (int d = 0; d < 128; ++d) s += a.WE[l][f * 128 + d] * a.BQ[l][d];
      a.bc[l][512 + f] = s;
    }
  } else {
    int l = (b - 827) >> 1;
    int j = ((b - 827) & 1) * 256 + tid;
    const float* src = (j < 128) ? a.BQ[l] : (j < 256) ? a.BK[l]
                     : (j < 384) ? a.BV[l] : a.BS[l];
    a.bc[l][j] = src[j & 127];
  }
}

// ---------------- typed stores / loads ----------------
__device__ inline void store4h(__half* p, float4 v) {
  __half2 h01 = __floats2half2_rn(v.x, v.y);
  __half2 h23 = __floats2half2_rn(v.z, v.w);
  uint2 u;
  u.x = *(unsigned int*)&h01;
  u.y = *(unsigned int*)&h23;
  *(uint2*)p = u;
}

__device__ inline void store8h(__half* p, float4 lo, float4 hi) {
  __half2 a = __floats2half2_rn(lo.x, lo.y);
  __half2 b = __floats2half2_rn(lo.z, lo.w);
  __half2 c = __floats2half2_rn(hi.x, hi.y);
  __half2 d = __floats2half2_rn(hi.z, hi.w);
  uint4 u;
  u.x = *(unsigned int*)&a;
  u.y = *(unsigned int*)&b;
  u.z = *(unsigned int*)&c;
  u.w = *(unsigned int*)&d;
  *(uint4*)p = u;
}

__device__ inline void load8h(const __half* p, float4& lo, float4& hi) {
  uint4 u = *(const uint4*)p;
  float2 a = __half22float2(*(__half2*)&u.x);
  float2 b = __half22float2(*(__half2*)&u.y);
  float2 c = __half22float2(*(__half2*)&u.z);
  float2 d = __half22float2(*(__half2*)&u.w);
  lo = make_float4(a.x, a.y, b.x, b.y);
  hi = make_float4(c.x, c.y, d.x, d.y);
}

// A-fragment loaders: fp32 converts, fp16 is a direct 16B load
__device__ inline half8 loadA(const float* p) {
  float4 f0 = *(const float4*)p;
  float4 f1 = *(const float4*)(p + 4);
  half8 a;
  a[0] = (_Float16)f0.x; a[1] = (_Float16)f0.y; a[2] = (_Float16)f0.z; a[3] = (_Float16)f0.w;
  a[4] = (_Float16)f1.x; a[5] = (_Float16)f1.y; a[6] = (_Float16)f1.z; a[7] = (_Float16)f1.w;
  return a;
}
__device__ inline half8 loadA(const __half* p) { return *(const half8*)p; }

// ---------------- MFMA GEMM (LDS-staged W chunks + optional 16-col t-tile) ----------------
// in [Nrows][K] (fp32 or fp16); Wt [(NCT*16 + (QKVS?16:0))][K] fp16; bias fp32.
// All matrix outputs fp16. QKVS: cols 0-127->oq, 128-255->ok, 256-383->ov,
// 384-511->os (may alias `in`: each lane fully reads its own row before any
// store), cols 512-527 -> qt fp32 [Nrows][16] (t = we@q per node).
template <typename AT, int K, int NCT, bool QKVS>
__global__ __launch_bounds__(256) void mfma_gemm_kernel(
    const AT* in, const __half* __restrict__ Wt, const float* __restrict__ bias,
    __half* __restrict__ oq, __half* __restrict__ ok, __half* __restrict__ ov,
    __half* os, float* __restrict__ qt) {
  constexpr int WST = K + 8;  // Wc row stride in halfs; (K+8)*2 bytes % 16 == 0
  __shared__ alignas(16) __half Wc[128 * WST];  // current 128-col W chunk
  const int tid = threadIdx.x;
  const int w = tid >> 6, l = tid & 63;
  const int lo = l & 15, hi = l >> 4;
  const size_t row = (size_t)blockIdx.x * 64 + w * 16 + lo;

  // A-side (h) fragments: 8 consecutive elems of own row per k-step
  half8 af[K / 32];
  #pragma unroll
  for (int s = 0; s < K / 32; ++s)
    af[s] = loadA(in + row * K + s * 32 + hi * 8);

  // chunk loop: 128 output cols per chunk, W chunk staged in LDS
  #pragma unroll 1
  for (int ch = 0; ch < NCT / 8; ++ch) {
    __syncthreads();  // protect Wc reuse across chunks
    #pragma unroll
    for (int i = 0; i < 128 * K / 8 / 256; ++i) {
      int idx = i * 256 + tid;
      int col = idx / (K / 8), kk = (idx % (K / 8)) * 8;
      *(uint4*)&Wc[col * WST + kk] =
          *(const uint4*)(Wt + (size_t)(ch * 128 + col) * K + kk);
    }
    __syncthreads();

    #pragma unroll
    for (int t = 0; t < 8; ++t) {
      f32x4 c = {0.f, 0.f, 0.f, 0.f};
      #pragma unroll
      for (int s = 0; s < K / 32; ++s) {
        half8 bf = *(const half8*)&Wc[(t * 16 + lo) * WST + s * 32 + hi * 8];
        c = __builtin_amdgcn_mfma_f32_16x16x32_f16(bf, af[s], c, 0, 0, 0);
      }
      const int col0 = ch * 128 + t * 16 + hi * 4;
      float4 b4 = *(const float4*)(bias + col0);
      float4 o;
      o.x = c[0] + b4.x; o.y = c[1] + b4.y; o.z = c[2] + b4.z; o.w = c[3] + b4.w;
      if (QKVS) {
        const int mid = col0 >> 7, cc = col0 & 127;
        if (mid == 0)      store4h(oq + row * 128 + cc, o);
        else if (mid == 1) store4h(ok + row * 128 + cc, o);
        else if (mid == 2) store4h(ov + row * 128 + cc, o);
        else               store4h(os + row * 128 + cc, o);
      } else {
        store4h(os + row * 128 + col0, o);
      }
    }
  }

  // t-tile: 16 extra cols (Wqe rows 512..527) -> qt[row][0..15]
  if constexpr (QKVS) {
    __syncthreads();  // last chunk's MFMAs done reading Wc
    {
      int col = tid >> 4;          // K/8 == 16 -> exactly 256 vec4 copies
      int kk = (tid & 15) * 8;
      *(uint4*)&Wc[col * WST + kk] =
          *(const uint4*)(Wt + (size_t)(512 + col) * K + kk);
    }
    __syncthreads();
    f32x4 c = {0.f, 0.f, 0.f, 0.f};
    #pragma unroll
    for (int s = 0; s < K / 32; ++s) {
      half8 bf = *(const half8*)&Wc[lo * WST + s * 32 + hi * 8];
      c = __builtin_amdgcn_mfma_f32_16x16x32_f16(bf, af[s], c, 0, 0, 0);
    }
    float4 b4 = *(const float4*)(bias + 512 + hi * 4);
    float4 o;
    o.x = c[0] + b4.x; o.y = c[1] + b4.y; o.z = c[2] + b4.z; o.w = c[3] + b4.w;
    *(float4*)(qt + row * 16 + hi * 4) = o;
  }
}

// ---------------- node-centric transformer conv: 4 nodes per wave ----------------
// 16-lane group per node (sequential ids -> wave reads 4 consecutive rows),
// 8 dims/lane. h (fp16) holds s on entry; writes relu(s + (accV+accE@we)/den).
__global__ __launch_bounds__(256) void node_kernel(
    const __half* __restrict__ q, const __half* __restrict__ k, const __half* __restrict__ v,
    __half* __restrict__ h, const float* __restrict__ edge_attr,
    const float* __restrict__ we, const float* __restrict__ tq,
    const int* __restrict__ offs, const int* __restrict__ csr_src,
    const int* __restrict__ csr_eid) {
  // we_s: stride-10 layout (feature f, lane-chunk sub, elem j) -> f*160+sub*10+j
  __shared__ float we_s[16 * 160];  // 10 KB, conflict-free reads
  for (int i = threadIdx.x; i < 2048; i += 256) {
    int f = i >> 7, d = i & 127;
    we_s[f * 160 + (d >> 3) * 10 + (d & 7)] = we[i];
  }
  __syncthreads();

  const int lane = threadIdx.x & 63;
  const int wid = threadIdx.x >> 6;
  const int g = lane >> 4, sub = lane & 15;
  const int nid = blockIdx.x * 16 + wid * 4 + g;
  const int d0 = sub * 8;
  const float inv_sqrt_d = 0.08838834764831845f;  // 1/sqrt(128)

  float4 qlo, qhi;
  load8h(q + (size_t)nid * D + d0, qlo, qhi);
  float4 slo, shi;
  load8h(h + (size_t)nid * D + d0, slo, shi);
  const float tf = tq[(size_t)nid * 16 + sub];

  const int eb = offs[nid], ee = offs[nid + 1];
  float m = -3.0e38f, den = 0.f, accE = 0.f;
  float4 alo = {0.f, 0.f, 0.f, 0.f}, ahi = {0.f, 0.f, 0.f, 0.f};

  // 2-deep pipeline over this group's edges
  float4 klon = {0,0,0,0}, khin = {0,0,0,0}, vlon = {0,0,0,0}, vhin = {0,0,0,0};
  float eafn = 0.f;
  int p = eb;
  if (p < ee) {
    int src = csr_src[p];
    int eid = csr_eid[p];
    load8h(k + (size_t)src * D + d0, klon, khin);
    load8h(v + (size_t)src * D + d0, vlon, vhin);
    eafn = edge_attr[(size_t)eid * 16 + sub];
  }
  while (p < ee) {
    float4 klo = klon, khi = khin, vlo = vlon, vhi = vhin;
    float eaf = eafn;
    ++p;
    if (p < ee) {
      int src = csr_src[p];
      int eid = csr_eid[p];
      load8h(k + (size_t)src * D + d0, klon, khin);
      load8h(v + (size_t)src * D + d0, vlon, vhin);
      eafn = edge_attr[(size_t)eid * 16 + sub];
    }
    float pa = qlo.x * klo.x + qlo.y * klo.y + qlo.z * klo.z + qlo.w * klo.w +
               qhi.x * khi.x + qhi.y * khi.y + qhi.z * khi.z + qhi.w * khi.w +
               eaf * tf;
    #pragma unroll
    for (int off = 8; off > 0; off >>= 1) pa += __shfl_xor(pa, off, 64);
    pa *= inv_sqrt_d;
    float mn = fmaxf(m, pa);
    float esc = __expf(m - mn);
    float ew = __expf(pa - mn);
    den = den * esc + ew;
    alo.x = alo.x * esc + ew * vlo.x;
    alo.y = alo.y * esc + ew * vlo.y;
    alo.z = alo.z * esc + ew * vlo.z;
    alo.w = alo.w * esc + ew * vlo.w;
    ahi.x = ahi.x * esc + ew * vhi.x;
    ahi.y = ahi.y * esc + ew * vhi.y;
    ahi.z = ahi.z * esc + ew * vhi.z;
    ahi.w = ahi.w * esc + ew * vhi.w;
    accE = accE * esc + ew * eaf;
    m = mn;
  }

  if (den > 0.f) {
    float inv = 1.0f / den;
    float4 elo = {0.f, 0.f, 0.f, 0.f}, ehi = {0.f, 0.f, 0.f, 0.f};
    const int gbase = lane & 48;
    const int wb = sub * 10;
    #pragma unroll
    for (int f = 0; f < 16; ++f) {
      float aE = __shfl(accE, gbase + f, 64);
      const float* wr = &we_s[f * 160 + wb];
      float2 w01 = *(const float2*)(wr + 0);
      float2 w23 = *(const float2*)(wr + 2);
      float2 w45 = *(const float2*)(wr + 4);
      float2 w67 = *(const float2*)(wr + 6);
      elo.x += aE * w01.x; elo.y += aE * w01.y; elo.z += aE * w23.x; elo.w += aE * w23.y;
      ehi.x += aE * w45.x; ehi.y += aE * w45.y; ehi.z += aE * w67.x; ehi.w += aE * w67.y;
    }
    slo.x += (alo.x + elo.x) * inv;
    slo.y += (alo.y + elo.y) * inv;
    slo.z += (alo.z + elo.z) * inv;
    slo.w += (alo.w + elo.w) * inv;
    shi.x += (ahi.x + ehi.x) * inv;
    shi.y += (ahi.y + ehi.y) * inv;
    shi.z += (ahi.z + ehi.z) * inv;
    shi.w += (ahi.w + ehi.w) * inv;
  }
  slo.x = fmaxf(slo.x, 0.f); slo.y = fmaxf(slo.y, 0.f);
  slo.z = fmaxf(slo.z, 0.f); slo.w = fmaxf(slo.w, 0.f);
  shi.x = fmaxf(shi.x, 0.f); shi.y = fmaxf(shi.y, 0.f);
  shi.z = fmaxf(shi.z, 0.f); shi.w = fmaxf(shi.w, 0.f);
  store8h(h + (size_t)nid * D + d0, slo, shi);
}

// ---------------- segmented mean-pool (batch sorted, h fp16) ----------------
__global__ __launch_bounds__(64) void pool_kernel(const __half* __restrict__ h,
                                                  const int* __restrict__ batch,
                                                  float* __restrict__ hg,
                                                  float* __restrict__ cnt, int n) {
  int base = blockIdx.x * 128;
  int lane = threadIdx.x;
  float2 acc = {0.f, 0.f};
  float run = 0.f;
  int cur = batch[base];
  for (int i = 0; i < 128; ++i) {
    int node = base + i;
    int g = batch[node];
    if (g != cur) {
      atomicAdd(&hg[(size_t)cur * D + 2 * lane], acc.x);
      atomicAdd(&hg[(size_t)cur * D + 2 * lane + 1], acc.y);
      if (lane == 0) atomicAdd(&cnt[cur], run);
      acc.x = acc.y = 0.f; run = 0.f; cur = g;
    }
    float2 hv = __half22float2(((const __half2*)h)[(size_t)node * 64 + lane]);
    acc.x += hv.x; acc.y += hv.y; run += 1.f;
  }
  atomicAdd(&hg[(size_t)cur * D + 2 * lane], acc.x);
  atomicAdd(&hg[(size_t)cur * D + 2 * lane + 1], acc.y);
  if (lane == 0) atomicAdd(&cnt[cur], run);
}

// ---------------- head: mean, fc2+relu, fc3 (one wave per graph) ----------------
__global__ __launch_bounds__(256) void head_kernel(const float* __restrict__ hg,
                                                   const float* __restrict__ cnt,
                                                   const float* __restrict__ w2,
                                                   const float* __restrict__ b2,
                                                   const float* __restrict__ w3,
                                                   const float* __restrict__ b3,
                                                   float* __restrict__ out) {
  __shared__ float w2s[128 * 16];
  __shared__ float rowb[4][128];
  for (int i = threadIdx.x; i < (128 * 16) / 4; i += 256)
    ((float4*)w2s)[i] = ((const float4*)w2)[i];
  int wid = threadIdx.x >> 6, lane = threadIdx.x & 63;
  int g = blockIdx.x * 4 + wid;
  float inv = 1.0f / fmaxf(cnt[g], 1.0f);
  rowb[wid][lane] = hg[(size_t)g * D + lane] * inv;
  rowb[wid][lane + 64] = hg[(size_t)g * D + 64 + lane] * inv;
  __syncthreads();
  float t = 0.f;
  if (lane < 16) {
    float a = b2[lane];
    for (int d = 0; d < 128; ++d) a += rowb[wid][d] * w2s[d * 16 + lane];
    t = fmaxf(a, 0.f) * w3[lane];
  }
  #pragma unroll
  for (int off = 8; off > 0; off >>= 1) t += __shfl_xor(t, off, 64);
  if (lane == 0) out[g] = t + b3[0];
}

// ---------------- launch ----------------
extern "C" void kernel_launch(void* const* d_in, const int* in_sizes, int n_in,
                              void* d_out, int out_size, void* d_ws, size_t ws_size,
                              hipStream_t stream) {
  const float* x = (const float*)d_in[0];
  const int* eidx = (const int*)d_in[1];
  const float* eattr = (const float*)d_in[2];
  const int* batch = (const int*)d_in[3];
  const float* fc1_w = (const float*)d_in[4];
  const float* fc1_b = (const float*)d_in[5];
  const float* WQ[3] = {(const float*)d_in[6], (const float*)d_in[15], (const float*)d_in[24]};
  const float* BQ[3] = {(const float*)d_in[7], (const float*)d_in[16], (const float*)d_in[25]};
  const float* WK[3] = {(const float*)d_in[8], (const float*)d_in[17], (const float*)d_in[26]};
  const float* BK[3] = {(const float*)d_in[9], (const float*)d_in[18], (const float*)d_in[27]};
  const float* WV[3] = {(const float*)d_in[10], (const float*)d_in[19], (const float*)d_in[28]};
  const float* BV[3] = {(const float*)d_in[11], (const float*)d_in[20], (const float*)d_in[29]};
  const float* WE[3] = {(const float*)d_in[12], (const float*)d_in[21], (const float*)d_in[30]};
  const float* WS[3] = {(const float*)d_in[13], (const float*)d_in[22], (const float*)d_in[31]};
  const float* BS[3] = {(const float*)d_in[14], (const float*)d_in[23], (const float*)d_in[32]};
  const float* fc2_w = (const float*)d_in[33];
  const float* fc2_b = (const float*)d_in[34];
  const float* fc3_w = (const float*)d_in[35];
  const float* fc3_b = (const float*)d_in[36];

  const int N = in_sizes[0] / 64;
  const int E = in_sizes[1] / 2;
  const int G = out_size;  // DIM_OUT = 1
  const int* srcs = eidx;
  const int* dsts = eidx + E;
  const size_t ND = (size_t)N * D;

  char* base = (char*)d_ws;
  size_t off = 0;
  auto alloc = [&](size_t bytes) {
    void* p = base + off;
    off = (off + bytes + 255) & ~(size_t)255;
    return p;
  };
  // zeroed region first: hg, cnt, counts, cursor
  float* hg = (float*)alloc((size_t)G * D * 4);
  float* cntf = (float*)alloc((size_t)G * 4);
  int* counts = (int*)alloc((size_t)N * 4);
  int* cursor = (int*)alloc((size_t)N * 4);
  size_t zero_bytes = off;
  int* incl = (int*)alloc((size_t)N * 4);
  int* offs = (int*)alloc((size_t)(N + 4) * 4);
  int* bsum = (int*)alloc(512 * 4);
  int* csr_src = (int*)alloc((size_t)E * 4);
  int* csr_eid = (int*)alloc((size_t)E * 4);
  __half* h = (__half*)alloc(ND * 2);
  __half* q = (__half*)alloc(ND * 2);
  __half* k = (__half*)alloc(ND * 2);
  __half* v = (__half*)alloc(ND * 2);
  float* qt = (float*)alloc((size_t)N * 16 * 4);
  __half* Wt[3];
  float* bc[3];
  for (int l = 0; l < 3; ++l) {
    Wt[l] = (__half*)alloc(528 * 128 * 2);  // q|k|v|s (512) + Wqe (16)
    bc[l] = (float*)alloc(544 * 4);         // 512 biases + 16 bqe
  }
  __half* fc1t = (__half*)alloc(128 * 64 * 2);
  if (off > ws_size) return;  // ws too small (diagnostic: stub-identical absmax)

  hipMemsetAsync(hg, 0, zero_bytes, stream);

  // fused weight prep (one launch)
  PrepArgs pa;
  for (int l = 0; l < 3; ++l) {
    pa.W[l * 4 + 0] = WQ[l];
    pa.W[l * 4 + 1] = WK[l];
    pa.W[l * 4 + 2] = WV[l];
    pa.W[l * 4 + 3] = WS[l];
    pa.WE[l] = WE[l];
    pa.BQ[l] = BQ[l]; pa.BK[l] = BK[l]; pa.BV[l] = BV[l]; pa.BS[l] = BS[l];
    pa.Wt[l] = Wt[l]; pa.bc[l] = bc[l];
  }
  pa.fc1w = fc1_w;
  pa.fc1t = fc1t;
  prep_kernel<<<833, 256, 0, stream>>>(pa);

  // CSR build (deterministic after sort)
  hist_kernel<<<E / 256, 256, 0, stream>>>(dsts, counts, E);
  scan_a_kernel<<<N / 256, 256, 0, stream>>>(counts, incl, bsum);
  scan_b_kernel<<<1, 512, 0, stream>>>(bsum);
  scan_c_kernel<<<N / 256, 256, 0, stream>>>(incl, counts, bsum, offs, N, E);
  scatter_kernel<<<E / 256, 256, 0, stream>>>(srcs, dsts, offs, cursor, csr_src, csr_eid, E);
  sort_kernel<<<N / 256, 256, 0, stream>>>(offs, csr_eid, csr_src, N);

  // fc1: h = x @ fc1_w + fc1_b  (MFMA, K=64, 128 cols, h fp16)
  mfma_gemm_kernel<float, 64, 8, false><<<N / 64, 256, 0, stream>>>(
      x, fc1t, fc1_b, nullptr, nullptr, nullptr, h, nullptr);

  // 3 transformer-conv layers
  for (int l = 0; l < 3; ++l) {
    mfma_gemm_kernel<__half, 128, 32, true><<<N / 64, 256, 0, stream>>>(
        h, Wt[l], bc[l], q, k, v, h, qt);
    node_kernel<<<N / 16, 256, 0, stream>>>(q, k, v, h, eattr, WE[l], qt,
                                            offs, csr_src, csr_eid);
  }

  // mean pool + head
  pool_kernel<<<N / 128, 64, 0, stream>>>(h, batch, hg, cntf, N);
  head_kernel<<<G / 4, 256, 0, stream>>>(hg, cntf, fc2_w, fc2_b, fc3_w, fc3_b, (float*)d_out);
}